// Round 1
// baseline (279.577 us; speedup 1.0000x reference)
//
#include <hip/hip_runtime.h>
#include <stdint.h>

typedef unsigned short ushort_t;
typedef __attribute__((ext_vector_type(8))) short short8;
typedef __attribute__((ext_vector_type(4))) short bf16x4;
typedef __attribute__((ext_vector_type(4))) float f32x4;

#define AS1 __attribute__((address_space(1)))
#define AS3 __attribute__((address_space(3)))

// async global->LDS, 16B per lane; LDS dest is wave-uniform base + lane*16
__device__ __forceinline__ void gl_lds16(const void* g, void* l) {
    __builtin_amdgcn_global_load_lds((const AS1 unsigned int*)g,
                                     (AS3 unsigned int*)l, 16, 0, 0);
}

__device__ __forceinline__ ushort_t f2bf(float f) {   // RNE f32 -> bf16
    union { float f; unsigned u; } v; v.f = f;
    unsigned r = v.u + 0x7fffu + ((v.u >> 16) & 1u);
    return (ushort_t)(r >> 16);
}

// ---------------------------------------------------------------------------
// Kernel 0 (merged prep): grid-sliced
// ---------------------------------------------------------------------------
__global__ __launch_bounds__(256) void prep_k(const float* __restrict__ inp,
                                              const float* __restrict__ Wo,
                                              const float* __restrict__ Wq,
                                              const float* __restrict__ Wk,
                                              const float* __restrict__ Wv,
                                              ushort_t* __restrict__ inp_bf,
                                              ushort_t* __restrict__ WoB,
                                              ushort_t* __restrict__ WT) {
    const int bx = blockIdx.x, tid = threadIdx.x;
    if (bx < 4608) {
        const float* src = (bx < 4096) ? inp : Wo;
        ushort_t* dst    = (bx < 4096) ? inp_bf : WoB;
        int i = ((bx < 4096 ? bx : bx - 4096) * 256 + tid) * 8;
        float4 a = *(const float4*)(src + i);
        float4 b = *(const float4*)(src + i + 4);
        short8 o;
        o[0] = (short)f2bf(a.x); o[1] = (short)f2bf(a.y);
        o[2] = (short)f2bf(a.z); o[3] = (short)f2bf(a.w);
        o[4] = (short)f2bf(b.x); o[5] = (short)f2bf(b.y);
        o[6] = (short)f2bf(b.z); o[7] = (short)f2bf(b.w);
        *(short8*)(dst + i) = o;
        return;
    }
    __shared__ ushort_t t[64 * 65];
    const int wb = bx - 4608;             // 0..767 : mat(3) x h(16) x etile(16)
    const int mat = wb >> 8;
    const int h   = (wb >> 4) & 15;
    const int et  = wb & 15;
    const float* W = (mat == 0 ? Wq : (mat == 1 ? Wk : Wv)) + h * (1024 * 64);
    const float* src = W + et * 64 * 64;
#pragma unroll
    for (int i = 0; i < 16; ++i) {
        int idx = i * 256 + tid;
        int e = idx >> 6, d = idx & 63;
        t[e * 65 + d] = f2bf(src[idx]);
    }
    __syncthreads();
    ushort_t* dst = WT + (mat * 16 + h) * (64 * 1024) + et * 64;
#pragma unroll
    for (int i = 0; i < 16; ++i) {
        int idx = i * 256 + tid;
        int d = idx >> 6, e = idx & 63;
        dst[d * 1024 + e] = t[e * 65 + d];
    }
}

// ---------------------------------------------------------------------------
// Kernel 2: UNIFIED QKV GEMM.
// NEW this round: single-barrier double-buffered staging (same mechanism as
// flash/outproj): prefetch tile it+1 at top of body, compute tile it, ONE
// barrier. The compiler-inserted vmcnt(0) drain at the barrier then waits on
// loads issued a full compute-body earlier -> staging latency hidden.
// LDS 2*(16+16)=64 KB -> 2 blocks/CU (8 waves/CU, >= current 6-wave avg).
// Also NEW: V epilogue transposes through the (now idle) LDS buffers so the
// Vt[b][h][d][s] store is 128B-contiguous short8 instead of 2B scatter at
// 4KB stride.
// ---------------------------------------------------------------------------
__global__ __launch_bounds__(256) void qkv_k(const ushort_t* A, const ushort_t* WT,
                                             ushort_t* Q, ushort_t* K, ushort_t* Vt) {
    __shared__ __align__(16) ushort_t As[2][128 * 64];   // 32 KB
    __shared__ __align__(16) ushort_t Bs[2][128 * 64];   // 32 KB
    const int tid = threadIdx.x, wave = tid >> 6, lane = tid & 63;
    const int ln15 = lane & 15, quad = lane >> 4;
    const int wm = wave >> 1, wn = wave & 1;
    const int lrow = lane >> 3, lcol = (lane & 7) * 8;
    const int m0 = blockIdx.x * 128, n0 = blockIdx.y * 128;

    f32x4 acc[4][4];
#pragma unroll
    for (int i = 0; i < 4; ++i)
#pragma unroll
        for (int j = 0; j < 4; ++j)
#pragma unroll
            for (int e = 0; e < 4; ++e) acc[i][j][e] = 0.f;

    // prologue: stage k0=0 into buf 0
#pragma unroll
    for (int i = 0; i < 4; ++i) {
        int br = i * 32 + wave * 8;
        gl_lds16(A  + (size_t)(m0 + br + lrow) * 1024 + lcol, &As[0][br * 64]);
        gl_lds16(WT + (size_t)(n0 + br + lrow) * 1024 + lcol, &Bs[0][br * 64]);
    }
    __syncthreads();   // buf0 staged (compiler drains vmcnt before barrier)

    for (int it = 0; it < 16; ++it) {
        const int cur = it & 1, nxt = cur ^ 1;
        if (it < 15) {   // prefetch next K-tile into the other buffer
            const int k0 = (it + 1) * 64;
#pragma unroll
            for (int i = 0; i < 4; ++i) {
                int br = i * 32 + wave * 8;
                gl_lds16(A  + (size_t)(m0 + br + lrow) * 1024 + k0 + lcol, &As[nxt][br * 64]);
                gl_lds16(WT + (size_t)(n0 + br + lrow) * 1024 + k0 + lcol, &Bs[nxt][br * 64]);
            }
        }
#pragma unroll
        for (int kk = 0; kk < 2; ++kk) {
            short8 a[4], b[4];
#pragma unroll
            for (int f = 0; f < 4; ++f)
                a[f] = *(const short8*)&As[cur][(wm * 64 + f * 16 + ln15) * 64 + kk * 32 + quad * 8];
#pragma unroll
            for (int f = 0; f < 4; ++f)
                b[f] = *(const short8*)&Bs[cur][(wn * 64 + f * 16 + ln15) * 64 + kk * 32 + quad * 8];
#pragma unroll
            for (int fm = 0; fm < 4; ++fm)
#pragma unroll
                for (int fn = 0; fn < 4; ++fn)
                    acc[fm][fn] = __builtin_amdgcn_mfma_f32_16x16x32_bf16(a[fm], b[fn], acc[fm][fn], 0, 0, 0);
        }
        __syncthreads();   // readers done with buf[cur] AND buf[nxt] staged
    }
    const int n_base = n0 + wn * 64;          // this wave's 64-col head block
    const int mat = n_base >> 10;             // 0:Q 1:K 2:V (uniform per wave)
    const int h   = (n_base >> 6) & 15;
    if (mat < 2) {
        ushort_t* dst = (mat == 0) ? Q : K;
        const float scale = (mat == 0) ? 0.125f : 1.0f;   // 1/sqrt(64) into Q
#pragma unroll
        for (int fm = 0; fm < 4; ++fm) {
#pragma unroll
            for (int r = 0; r < 4; ++r) {
                int mg = m0 + wm * 64 + fm * 16 + quad * 4 + r;
                int bi = mg >> 11, s = mg & 2047;
                size_t base = ((size_t)(bi * 16 + h) * 2048 + s) * 64;
#pragma unroll
                for (int fn = 0; fn < 4; ++fn)
                    dst[base + fn * 16 + ln15] = f2bf(acc[fm][fn][r] * scale);
            }
        }
    } else {
        // V transposed: Vt[b][h][d][s]. Transpose through this wave's private
        // LDS region (staging buffers are dead after the final barrier) so the
        // global store is short8 along s (128B contiguous per d-row).
        ushort_t* tb = (wave < 2) ? &As[wave][0] : &Bs[wave - 2][0];  // 8192 el >= 64*72
#pragma unroll
        for (int fn = 0; fn < 4; ++fn)
#pragma unroll
            for (int fm = 0; fm < 4; ++fm) {
                bf16x4 pk;
#pragma unroll
                for (int r = 0; r < 4; ++r) pk[r] = (short)f2bf(acc[fm][fn][r]);
                // row = d (fn*16+ln15), col = s_local (fm*16+quad*4..+3)
                *(bf16x4*)&tb[(fn * 16 + ln15) * 72 + fm * 16 + quad * 4] = pk;
            }
        // wave-private region: no barrier needed, compiler orders via lgkmcnt
        const int s0 = m0 + wm * 64;
        const int bi = s0 >> 11, sb = s0 & 2047;
#pragma unroll
        for (int p = 0; p < 8; ++p) {
            int d  = p * 8 + (lane >> 3);
            int sc = (lane & 7) * 8;
            short8 vv = *(const short8*)&tb[d * 72 + sc];
            *(short8*)&Vt[((size_t)(bi * 16 + h) * 64 + d) * 2048 + sb + sc] = vv;
        }
    }
}

// ---------------------------------------------------------------------------
// Kernel 3: causal flash attention, S^T form, fixed-max softmax,
// SINGLE-BARRIER DOUBLE-BUFFERED K/V staging (unchanged this round).
// LDS: 2*8 + 2*8 + 18 = 50 KB -> 3 blocks/CU.
// ---------------------------------------------------------------------------
__global__ __launch_bounds__(256, 3) void flash_k(const ushort_t* Q, const ushort_t* K,
                                                  const ushort_t* Vt, ushort_t* Aout) {
    __shared__ __align__(16) ushort_t Ks[2][64 * 64];   // 16 KB
    __shared__ __align__(16) ushort_t Vts[2][64 * 64];  // 16 KB
    __shared__ __align__(16) ushort_t PT[4][32 * 72];   // 18 KB per-wave P^T
    const int tid = threadIdx.x, wave = tid >> 6, lane = tid & 63;
    const int ln15 = lane & 15, quad = lane >> 4;
    const int bx = blockIdx.x;
    const int qt = 15 - (bx >> 6);             // big tiles dispatch first
    const int bh = bx & 63;
    const int qw = qt * 128 + wave * 32;       // this wave's first q row
    const ushort_t* Kb = K + (size_t)bh * 2048 * 64;
    const ushort_t* Vb = Vt + (size_t)bh * 64 * 2048;
    ushort_t* myPT = PT[wave];
    const int srow = tid >> 3, c8 = (tid & 7) * 8;   // staging coords

    // Q-fragments direct from global
    short8 qf[2][2];
    {
        const ushort_t* Qb = Q + (size_t)bh * 2048 * 64;
#pragma unroll
        for (int qs = 0; qs < 2; ++qs)
#pragma unroll
            for (int kk = 0; kk < 2; ++kk)
                qf[qs][kk] = *(const short8*)&Qb[(size_t)(qw + qs * 16 + ln15) * 64 + kk * 32 + quad * 8];
    }

    f32x4 o[4][2];
#pragma unroll
    for (int dt = 0; dt < 4; ++dt)
#pragma unroll
        for (int qs = 0; qs < 2; ++qs)
#pragma unroll
            for (int e = 0; e < 4; ++e) o[dt][qs][e] = 0.f;
    float l_s[2] = {0.f, 0.f};

    const int ktEnd = 2 * qt + 2;
    // prologue: stage kt=0 into buf 0
    gl_lds16(Kb + (size_t)srow * 64 + c8,        &Ks[0][srow * 64 + c8]);
    gl_lds16(Kb + (size_t)(32 + srow) * 64 + c8, &Ks[0][(32 + srow) * 64 + c8]);
    gl_lds16(Vb + (size_t)srow * 2048 + c8,        &Vts[0][srow * 64 + c8]);
    gl_lds16(Vb + (size_t)(32 + srow) * 2048 + c8, &Vts[0][(32 + srow) * 64 + c8]);
    __syncthreads();   // buf0 staged (compiler drains vmcnt before barrier)

    for (int kt = 0; kt < ktEnd; ++kt) {
        const int cur = kt & 1, nxt = cur ^ 1;
        if (kt + 1 < ktEnd) {   // prefetch next tile into the other buffer
            int kn = kt + 1;
            gl_lds16(Kb + (size_t)(kn * 64 + srow) * 64 + c8,      &Ks[nxt][srow * 64 + c8]);
            gl_lds16(Kb + (size_t)(kn * 64 + 32 + srow) * 64 + c8, &Ks[nxt][(32 + srow) * 64 + c8]);
            gl_lds16(Vb + (size_t)srow * 2048 + kn * 64 + c8,        &Vts[nxt][srow * 64 + c8]);
            gl_lds16(Vb + (size_t)(32 + srow) * 2048 + kn * 64 + c8, &Vts[nxt][(32 + srow) * 64 + c8]);
        }
        if (kt * 64 <= qw + 31) {              // wave not fully masked
            // S^T = K . Q^T   (C: row=key=quad*4+r, col=q=ln15)
            f32x4 sc[4][2];
#pragma unroll
            for (int ks = 0; ks < 4; ++ks) {
#pragma unroll
                for (int qs = 0; qs < 2; ++qs)
#pragma unroll
                    for (int e = 0; e < 4; ++e) sc[ks][qs][e] = 0.f;
#pragma unroll
                for (int kk = 0; kk < 2; ++kk) {
                    short8 kf = *(const short8*)&Ks[cur][(ks * 16 + ln15) * 64 + kk * 32 + quad * 8];
#pragma unroll
                    for (int qs = 0; qs < 2; ++qs)
                        sc[ks][qs] = __builtin_amdgcn_mfma_f32_16x16x32_bf16(kf, qf[qs][kk], sc[ks][qs], 0, 0, 0);
                }
            }
            if (kt * 64 + 63 > qw) {           // diagonal: causal mask
#pragma unroll
                for (int ks = 0; ks < 4; ++ks)
#pragma unroll
                    for (int qs = 0; qs < 2; ++qs) {
                        int qg = qw + qs * 16 + ln15;
#pragma unroll
                        for (int r = 0; r < 4; ++r) {
                            int kg = kt * 64 + ks * 16 + quad * 4 + r;
                            if (kg > qg) sc[ks][qs][r] = -1e30f;
                        }
                    }
            }
            // fixed-max softmax: p = exp(s); per-lane l; pack P^T
#pragma unroll
            for (int qs = 0; qs < 2; ++qs) {
#pragma unroll
                for (int ks = 0; ks < 4; ++ks) {
                    bf16x4 pk;
#pragma unroll
                    for (int r = 0; r < 4; ++r) {
                        float p = __expf(sc[ks][qs][r]);
                        l_s[qs] += p;
                        pk[r] = (short)f2bf(p);
                    }
                    *(bf16x4*)&myPT[(qs * 16 + ln15) * 72 + ks * 16 + quad * 4] = pk;
                }
            }
            // O^T += V^T . P^T
            short8 pf[2][2];
#pragma unroll
            for (int qs = 0; qs < 2; ++qs)
#pragma unroll
                for (int kk = 0; kk < 2; ++kk)
                    pf[qs][kk] = *(const short8*)&myPT[(qs * 16 + ln15) * 72 + kk * 32 + quad * 8];
#pragma unroll
            for (int dt = 0; dt < 4; ++dt)
#pragma unroll
                for (int kk = 0; kk < 2; ++kk) {
                    short8 vf = *(const short8*)&Vts[cur][(dt * 16 + ln15) * 64 + kk * 32 + quad * 8];
#pragma unroll
                    for (int qs = 0; qs < 2; ++qs)
                        o[dt][qs] = __builtin_amdgcn_mfma_f32_16x16x32_bf16(vf, pf[qs][kk], o[dt][qs], 0, 0, 0);
                }
        }
        __syncthreads();   // readers done with buf[cur] AND buf[nxt] staged
    }
    // epilogue: reduce l across quads, O^T -> LDS with 1/l, coalesced out
#pragma unroll
    for (int qs = 0; qs < 2; ++qs) {
        float l = l_s[qs];
        l += __shfl_xor(l, 16);
        l += __shfl_xor(l, 32);
        float inv = 1.f / l;
#pragma unroll
        for (int dt = 0; dt < 4; ++dt) {
            bf16x4 pk;
#pragma unroll
            for (int r = 0; r < 4; ++r) pk[r] = (short)f2bf(o[dt][qs][r] * inv);
            *(bf16x4*)&myPT[(qs * 16 + ln15) * 72 + dt * 16 + quad * 4] = pk;
        }
    }
    const int bi = bh >> 4, h = bh & 15;
#pragma unroll
    for (int p = 0; p < 4; ++p) {
        int row = p * 8 + (lane >> 3);
        int cc = (lane & 7) * 8;
        short8 vv = *(const short8*)&myPT[row * 72 + cc];
        int qg = qw + row;
        *(short8*)&Aout[((size_t)bi * 2048 + qg) * 1024 + h * 64 + cc] = vv;
    }
}

// ---------------------------------------------------------------------------
// Kernel 4: out(f32) = attn_bf[8192x1024] * WoB^T + bo(f32).
// NEW this round: 128x128 tile (was 64x128) -> arithmetic intensity 64 FLOP/B,
// same single-barrier double-buffered staging. LDS 2*(16+16)=64 KB -> 2/CU.
// ---------------------------------------------------------------------------
__global__ __launch_bounds__(256) void outproj_k(const ushort_t* A, const ushort_t* WoB,
                                                 const float* bo, float* Out) {
    __shared__ __align__(16) ushort_t As[2][128 * 64];   // 32 KB
    __shared__ __align__(16) ushort_t Bs[2][128 * 64];   // 32 KB
    const int tid = threadIdx.x, wave = tid >> 6, lane = tid & 63;
    const int ln15 = lane & 15, quad = lane >> 4;
    const int wm = wave >> 1, wn = wave & 1;
    const int lrow = lane >> 3, lcol = (lane & 7) * 8;
    const int m0 = blockIdx.x * 128, n0 = blockIdx.y * 128;

    f32x4 acc[4][4];
#pragma unroll
    for (int i = 0; i < 4; ++i)
#pragma unroll
        for (int j = 0; j < 4; ++j)
#pragma unroll
            for (int e = 0; e < 4; ++e) acc[i][j][e] = 0.f;

    // prologue: stage k0=0 into buf 0
#pragma unroll
    for (int i = 0; i < 4; ++i) {
        int br = i * 32 + wave * 8;
        gl_lds16(A   + (size_t)(m0 + br + lrow) * 1024 + lcol, &As[0][br * 64]);
        gl_lds16(WoB + (size_t)(n0 + br + lrow) * 1024 + lcol, &Bs[0][br * 64]);
    }
    __syncthreads();

    for (int it = 0; it < 16; ++it) {
        const int cur = it & 1, nxt = cur ^ 1;
        if (it < 15) {
            const int k0 = (it + 1) * 64;
#pragma unroll
            for (int i = 0; i < 4; ++i) {
                int br = i * 32 + wave * 8;
                gl_lds16(A   + (size_t)(m0 + br + lrow) * 1024 + k0 + lcol, &As[nxt][br * 64]);
                gl_lds16(WoB + (size_t)(n0 + br + lrow) * 1024 + k0 + lcol, &Bs[nxt][br * 64]);
            }
        }
#pragma unroll
        for (int kk = 0; kk < 2; ++kk) {
            short8 a[4], b[4];
#pragma unroll
            for (int f = 0; f < 4; ++f)
                a[f] = *(const short8*)&As[cur][(wm * 64 + f * 16 + ln15) * 64 + kk * 32 + quad * 8];
#pragma unroll
            for (int f = 0; f < 4; ++f)
                b[f] = *(const short8*)&Bs[cur][(wn * 64 + f * 16 + ln15) * 64 + kk * 32 + quad * 8];
#pragma unroll
            for (int fm = 0; fm < 4; ++fm)
#pragma unroll
                for (int fn = 0; fn < 4; ++fn)
                    acc[fm][fn] = __builtin_amdgcn_mfma_f32_16x16x32_bf16(a[fm], b[fn], acc[fm][fn], 0, 0, 0);
        }
        __syncthreads();
    }
#pragma unroll
    for (int fn = 0; fn < 4; ++fn) {
        int n = n0 + wn * 64 + fn * 16 + ln15;
        float bias = bo[n];
#pragma unroll
        for (int fm = 0; fm < 4; ++fm)
#pragma unroll
            for (int r = 0; r < 4; ++r) {
                int mg = m0 + wm * 64 + fm * 16 + quad * 4 + r;
                Out[(size_t)mg * 1024 + n] = acc[fm][fn][r] + bias;
            }
    }
}

// ---------------------------------------------------------------------------
extern "C" void kernel_launch(void* const* d_in, const int* in_sizes, int n_in,
                              void* d_out, int out_size, void* d_ws, size_t ws_size,
                              hipStream_t stream) {
    (void)in_sizes; (void)n_in; (void)out_size; (void)ws_size;
    const float* inp = (const float*)d_in[0];   // [4,2048,1024] f32
    const float* Wq  = (const float*)d_in[1];   // [16,1024,64]  f32
    const float* Wk  = (const float*)d_in[2];
    const float* Wv  = (const float*)d_in[3];
    const float* Wo  = (const float*)d_in[4];   // [1024,1024]   f32
    const float* bo  = (const float*)d_in[5];   // [1024]        f32
    float* out = (float*)d_out;                  // [4,2048,1024] f32

    ushort_t* ws = (ushort_t*)d_ws;
    ushort_t* R0  = ws;                       // 8,388,608 el (inp_bf, then At)
    ushort_t* WT  = R0  + 8388608;            // [3][16][64][1024]
    ushort_t* WoB = WT  + 3145728;            // [1024][1024]
    ushort_t* Qb  = WoB + 1048576;            // [4][16][2048][64]
    ushort_t* Kb  = Qb  + 8388608;            // [4][16][2048][64]
    ushort_t* Vtb = Kb  + 8388608;            // [4][16][64][2048]

    ushort_t* inp_bf = R0;
    ushort_t* At     = R0;

    prep_k<<<5376, 256, 0, stream>>>(inp, Wo, Wq, Wk, Wv, inp_bf, WoB, WT);
    qkv_k<<<dim3(64, 24), 256, 0, stream>>>(inp_bf, WT, Qb, Kb, Vtb);
    flash_k<<<dim3(1024), 256, 0, stream>>>(Qb, Kb, Vtb, At);
    outproj_k<<<dim3(64, 8), 256, 0, stream>>>(At, WoB, bo, out);
}

// Round 2
// 264.902 us; speedup vs baseline: 1.0554x; 1.0554x over previous
//
#include <hip/hip_runtime.h>
#include <stdint.h>

typedef unsigned short ushort_t;
typedef __attribute__((ext_vector_type(8))) short short8;
typedef __attribute__((ext_vector_type(4))) short bf16x4;
typedef __attribute__((ext_vector_type(4))) float f32x4;

#define AS1 __attribute__((address_space(1)))
#define AS3 __attribute__((address_space(3)))

// async global->LDS, 16B per lane; LDS dest is wave-uniform base + lane*16
__device__ __forceinline__ void gl_lds16(const void* g, void* l) {
    __builtin_amdgcn_global_load_lds((const AS1 unsigned int*)g,
                                     (AS3 unsigned int*)l, 16, 0, 0);
}

__device__ __forceinline__ ushort_t f2bf(float f) {   // RNE f32 -> bf16
    union { float f; unsigned u; } v; v.f = f;
    unsigned r = v.u + 0x7fffu + ((v.u >> 16) & 1u);
    return (ushort_t)(r >> 16);
}

// ---------------------------------------------------------------------------
// Kernel 0 (merged prep): grid-sliced
// ---------------------------------------------------------------------------
__global__ __launch_bounds__(256) void prep_k(const float* __restrict__ inp,
                                              const float* __restrict__ Wo,
                                              const float* __restrict__ Wq,
                                              const float* __restrict__ Wk,
                                              const float* __restrict__ Wv,
                                              ushort_t* __restrict__ inp_bf,
                                              ushort_t* __restrict__ WoB,
                                              ushort_t* __restrict__ WT) {
    const int bx = blockIdx.x, tid = threadIdx.x;
    if (bx < 4608) {
        const float* src = (bx < 4096) ? inp : Wo;
        ushort_t* dst    = (bx < 4096) ? inp_bf : WoB;
        int i = ((bx < 4096 ? bx : bx - 4096) * 256 + tid) * 8;
        float4 a = *(const float4*)(src + i);
        float4 b = *(const float4*)(src + i + 4);
        short8 o;
        o[0] = (short)f2bf(a.x); o[1] = (short)f2bf(a.y);
        o[2] = (short)f2bf(a.z); o[3] = (short)f2bf(a.w);
        o[4] = (short)f2bf(b.x); o[5] = (short)f2bf(b.y);
        o[6] = (short)f2bf(b.z); o[7] = (short)f2bf(b.w);
        *(short8*)(dst + i) = o;
        return;
    }
    __shared__ ushort_t t[64 * 65];
    const int wb = bx - 4608;             // 0..767 : mat(3) x h(16) x etile(16)
    const int mat = wb >> 8;
    const int h   = (wb >> 4) & 15;
    const int et  = wb & 15;
    const float* W = (mat == 0 ? Wq : (mat == 1 ? Wk : Wv)) + h * (1024 * 64);
    const float* src = W + et * 64 * 64;
#pragma unroll
    for (int i = 0; i < 16; ++i) {
        int idx = i * 256 + tid;
        int e = idx >> 6, d = idx & 63;
        t[e * 65 + d] = f2bf(src[idx]);
    }
    __syncthreads();
    ushort_t* dst = WT + (mat * 16 + h) * (64 * 1024) + et * 64;
#pragma unroll
    for (int i = 0; i < 16; ++i) {
        int idx = i * 256 + tid;
        int d = idx >> 6, e = idx & 63;
        dst[d * 1024 + e] = t[e * 65 + d];
    }
}

// ---------------------------------------------------------------------------
// Kernel 2: UNIFIED QKV GEMM — counted-vmcnt deep pipeline (T3+T4+T5).
// BM=256 x BN=128, BK=32, 512 threads (8 waves of 64x64). Ring of 4 LDS
// subtile buffers (96 KB), prefetch lookahead = 3 subtiles, vmcnt(6) counted
// waits (never 0 in steady state), ONE raw s_barrier per phase, setprio(1)
// around the 16-MFMA cluster.
// Safety: reads of subtile t are gated by every wave's own vmcnt confirm of
// t (issued one phase earlier) + barrier; stage of t+3 overwrites buf of
// t-1, whose reads completed (lgkmcnt before MFMA) before the barrier that
// precedes the stage issue. Tail peel: vmcnt(3) at t=29, vmcnt(0) at t=30.
// [256][32] LDS layout (64B row stride) -> wave b128 reads at the 8-cy LDS
// floor, no 128B-stride 16-way conflicts.
// Grid 32x24 = 768 blocks = exactly 3 balanced rounds at 1 block/CU.
// ---------------------------------------------------------------------------
__global__ __launch_bounds__(512, 2) void qkv_k(const ushort_t* __restrict__ A,
                                                const ushort_t* __restrict__ WT,
                                                ushort_t* __restrict__ Q,
                                                ushort_t* __restrict__ K,
                                                ushort_t* __restrict__ Vt) {
    __shared__ __align__(16) ushort_t ring[49152];   // 4 x (A 256x32 + B 128x32) = 96 KB
    const int tid = threadIdx.x, wave = tid >> 6, lane = tid & 63;
    const int ln15 = lane & 15, quad = lane >> 4;
    const int wm = wave >> 1, wn = wave & 1;         // 4M x 2N waves, 64x64 each
    // XCD-aware bijective swizzle of the 32x24 grid (768 % 8 == 0)
    const int flat = blockIdx.y * 32 + blockIdx.x;
    const int nfb  = (flat & 7) * 96 + (flat >> 3);
    const int m0 = (nfb & 31) * 256, n0 = (nfb >> 5) * 128;

    // staging coords: 512 threads, 16B chunks; chunk c -> row c>>2, col (c&3)*8
    const int sa_row = wave * 16 + (lane >> 2);
    const int sa_col = (lane & 3) * 8;
    const int woff   = wave * 512;                    // wave-uniform LDS chunk base (elems)

    f32x4 acc[4][4];
#pragma unroll
    for (int i = 0; i < 4; ++i)
#pragma unroll
        for (int j = 0; j < 4; ++j)
#pragma unroll
            for (int e = 0; e < 4; ++e) acc[i][j][e] = 0.f;

    auto stage = [&](int t) {
        const int kb = t * 32;
        ushort_t* buf = &ring[(t & 3) * 12288];
        gl_lds16(A  + (size_t)(m0 + sa_row)       * 1024 + kb + sa_col, buf + woff);
        gl_lds16(A  + (size_t)(m0 + 128 + sa_row) * 1024 + kb + sa_col, buf + 4096 + woff);
        gl_lds16(WT + (size_t)(n0 + sa_row)       * 1024 + kb + sa_col, buf + 8192 + woff);
    };

    // prologue: 3 subtiles in flight, confirm t0 (leave t1,t2 = 6 loads flying)
    stage(0); stage(1); stage(2);
    asm volatile("s_waitcnt vmcnt(6)" ::: "memory");
    __builtin_amdgcn_s_barrier();
    __builtin_amdgcn_sched_barrier(0);

    for (int t = 0; t < 32; ++t) {
        const ushort_t* buf = &ring[(t & 3) * 12288];
        short8 a[4], b[4];
#pragma unroll
        for (int f = 0; f < 4; ++f)
            a[f] = *(const short8*)&buf[(wm * 64 + f * 16 + ln15) * 32 + quad * 8];
#pragma unroll
        for (int f = 0; f < 4; ++f)
            b[f] = *(const short8*)&buf[8192 + (wn * 64 + f * 16 + ln15) * 32 + quad * 8];
        if (t + 3 < 32) stage(t + 3);
        // confirm subtile t+1 for next phase; counted (never 0 until tail)
        if (t < 29)       asm volatile("s_waitcnt vmcnt(6)" ::: "memory");
        else if (t == 29) asm volatile("s_waitcnt vmcnt(3)" ::: "memory");
        else if (t == 30) asm volatile("s_waitcnt vmcnt(0)" ::: "memory");
        __builtin_amdgcn_s_setprio(1);
#pragma unroll
        for (int fm = 0; fm < 4; ++fm)
#pragma unroll
            for (int fn = 0; fn < 4; ++fn)
                acc[fm][fn] = __builtin_amdgcn_mfma_f32_16x16x32_bf16(a[fm], b[fn], acc[fm][fn], 0, 0, 0);
        __builtin_amdgcn_s_setprio(0);
        __builtin_amdgcn_s_barrier();
        __builtin_amdgcn_sched_barrier(0);
    }

    const int n_base = n0 + wn * 64;          // this wave's 64-col head block
    const int mat = n_base >> 10;             // 0:Q 1:K 2:V (uniform per wave)
    const int h   = (n_base >> 6) & 15;
    if (mat < 2) {
        ushort_t* dst = (mat == 0) ? Q : K;
        const float scale = (mat == 0) ? 0.125f : 1.0f;   // 1/sqrt(64) into Q
#pragma unroll
        for (int fm = 0; fm < 4; ++fm) {
#pragma unroll
            for (int r = 0; r < 4; ++r) {
                int mg = m0 + wm * 64 + fm * 16 + quad * 4 + r;
                int bi = mg >> 11, s = mg & 2047;
                size_t base = ((size_t)(bi * 16 + h) * 2048 + s) * 64;
#pragma unroll
                for (int fn = 0; fn < 4; ++fn)
                    dst[base + fn * 16 + ln15] = f2bf(acc[fm][fn][r] * scale);
            }
        }
    } else {
        // V transposed: Vt[b][h][d][s]. Transpose through this wave's private
        // LDS scratch (ring is dead after the final barrier) so the global
        // store is short8 along s (128B contiguous per d-row).
        ushort_t* tb = &ring[wave * 6144];    // 12KB/wave >= 64*72 elems
#pragma unroll
        for (int fn = 0; fn < 4; ++fn)
#pragma unroll
            for (int fm = 0; fm < 4; ++fm) {
                bf16x4 pk;
#pragma unroll
                for (int r = 0; r < 4; ++r) pk[r] = (short)f2bf(acc[fm][fn][r]);
                // row = d (fn*16+ln15), col = s_local (fm*16+quad*4..+3)
                *(bf16x4*)&tb[(fn * 16 + ln15) * 72 + fm * 16 + quad * 4] = pk;
            }
        // wave-private region: no barrier needed, compiler orders via lgkmcnt
        const int s0 = m0 + wm * 64;
        const int bi = s0 >> 11, sb = s0 & 2047;
#pragma unroll
        for (int p = 0; p < 8; ++p) {
            int d  = p * 8 + (lane >> 3);
            int sc = (lane & 7) * 8;
            short8 vv = *(const short8*)&tb[d * 72 + sc];
            *(short8*)&Vt[((size_t)(bi * 16 + h) * 64 + d) * 2048 + sb + sc] = vv;
        }
    }
}

// ---------------------------------------------------------------------------
// Kernel 3: causal flash attention, S^T form, fixed-max softmax,
// SINGLE-BARRIER DOUBLE-BUFFERED K/V staging (unchanged this round).
// LDS: 2*8 + 2*8 + 18 = 50 KB -> 3 blocks/CU.
// ---------------------------------------------------------------------------
__global__ __launch_bounds__(256, 3) void flash_k(const ushort_t* Q, const ushort_t* K,
                                                  const ushort_t* Vt, ushort_t* Aout) {
    __shared__ __align__(16) ushort_t Ks[2][64 * 64];   // 16 KB
    __shared__ __align__(16) ushort_t Vts[2][64 * 64];  // 16 KB
    __shared__ __align__(16) ushort_t PT[4][32 * 72];   // 18 KB per-wave P^T
    const int tid = threadIdx.x, wave = tid >> 6, lane = tid & 63;
    const int ln15 = lane & 15, quad = lane >> 4;
    const int bx = blockIdx.x;
    const int qt = 15 - (bx >> 6);             // big tiles dispatch first
    const int bh = bx & 63;
    const int qw = qt * 128 + wave * 32;       // this wave's first q row
    const ushort_t* Kb = K + (size_t)bh * 2048 * 64;
    const ushort_t* Vb = Vt + (size_t)bh * 64 * 2048;
    ushort_t* myPT = PT[wave];
    const int srow = tid >> 3, c8 = (tid & 7) * 8;   // staging coords

    // Q-fragments direct from global
    short8 qf[2][2];
    {
        const ushort_t* Qb = Q + (size_t)bh * 2048 * 64;
#pragma unroll
        for (int qs = 0; qs < 2; ++qs)
#pragma unroll
            for (int kk = 0; kk < 2; ++kk)
                qf[qs][kk] = *(const short8*)&Qb[(size_t)(qw + qs * 16 + ln15) * 64 + kk * 32 + quad * 8];
    }

    f32x4 o[4][2];
#pragma unroll
    for (int dt = 0; dt < 4; ++dt)
#pragma unroll
        for (int qs = 0; qs < 2; ++qs)
#pragma unroll
            for (int e = 0; e < 4; ++e) o[dt][qs][e] = 0.f;
    float l_s[2] = {0.f, 0.f};

    const int ktEnd = 2 * qt + 2;
    // prologue: stage kt=0 into buf 0
    gl_lds16(Kb + (size_t)srow * 64 + c8,        &Ks[0][srow * 64 + c8]);
    gl_lds16(Kb + (size_t)(32 + srow) * 64 + c8, &Ks[0][(32 + srow) * 64 + c8]);
    gl_lds16(Vb + (size_t)srow * 2048 + c8,        &Vts[0][srow * 64 + c8]);
    gl_lds16(Vb + (size_t)(32 + srow) * 2048 + c8, &Vts[0][(32 + srow) * 64 + c8]);
    __syncthreads();   // buf0 staged (compiler drains vmcnt before barrier)

    for (int kt = 0; kt < ktEnd; ++kt) {
        const int cur = kt & 1, nxt = cur ^ 1;
        if (kt + 1 < ktEnd) {   // prefetch next tile into the other buffer
            int kn = kt + 1;
            gl_lds16(Kb + (size_t)(kn * 64 + srow) * 64 + c8,      &Ks[nxt][srow * 64 + c8]);
            gl_lds16(Kb + (size_t)(kn * 64 + 32 + srow) * 64 + c8, &Ks[nxt][(32 + srow) * 64 + c8]);
            gl_lds16(Vb + (size_t)srow * 2048 + kn * 64 + c8,        &Vts[nxt][srow * 64 + c8]);
            gl_lds16(Vb + (size_t)(32 + srow) * 2048 + kn * 64 + c8, &Vts[nxt][(32 + srow) * 64 + c8]);
        }
        if (kt * 64 <= qw + 31) {              // wave not fully masked
            // S^T = K . Q^T   (C: row=key=quad*4+r, col=q=ln15)
            f32x4 sc[4][2];
#pragma unroll
            for (int ks = 0; ks < 4; ++ks) {
#pragma unroll
                for (int qs = 0; qs < 2; ++qs)
#pragma unroll
                    for (int e = 0; e < 4; ++e) sc[ks][qs][e] = 0.f;
#pragma unroll
                for (int kk = 0; kk < 2; ++kk) {
                    short8 kf = *(const short8*)&Ks[cur][(ks * 16 + ln15) * 64 + kk * 32 + quad * 8];
#pragma unroll
                    for (int qs = 0; qs < 2; ++qs)
                        sc[ks][qs] = __builtin_amdgcn_mfma_f32_16x16x32_bf16(kf, qf[qs][kk], sc[ks][qs], 0, 0, 0);
                }
            }
            if (kt * 64 + 63 > qw) {           // diagonal: causal mask
#pragma unroll
                for (int ks = 0; ks < 4; ++ks)
#pragma unroll
                    for (int qs = 0; qs < 2; ++qs) {
                        int qg = qw + qs * 16 + ln15;
#pragma unroll
                        for (int r = 0; r < 4; ++r) {
                            int kg = kt * 64 + ks * 16 + quad * 4 + r;
                            if (kg > qg) sc[ks][qs][r] = -1e30f;
                        }
                    }
            }
            // fixed-max softmax: p = exp(s); per-lane l; pack P^T
#pragma unroll
            for (int qs = 0; qs < 2; ++qs) {
#pragma unroll
                for (int ks = 0; ks < 4; ++ks) {
                    bf16x4 pk;
#pragma unroll
                    for (int r = 0; r < 4; ++r) {
                        float p = __expf(sc[ks][qs][r]);
                        l_s[qs] += p;
                        pk[r] = (short)f2bf(p);
                    }
                    *(bf16x4*)&myPT[(qs * 16 + ln15) * 72 + ks * 16 + quad * 4] = pk;
                }
            }
            // O^T += V^T . P^T
            short8 pf[2][2];
#pragma unroll
            for (int qs = 0; qs < 2; ++qs)
#pragma unroll
                for (int kk = 0; kk < 2; ++kk)
                    pf[qs][kk] = *(const short8*)&myPT[(qs * 16 + ln15) * 72 + kk * 32 + quad * 8];
#pragma unroll
            for (int dt = 0; dt < 4; ++dt)
#pragma unroll
                for (int kk = 0; kk < 2; ++kk) {
                    short8 vf = *(const short8*)&Vts[cur][(dt * 16 + ln15) * 64 + kk * 32 + quad * 8];
#pragma unroll
                    for (int qs = 0; qs < 2; ++qs)
                        o[dt][qs] = __builtin_amdgcn_mfma_f32_16x16x32_bf16(vf, pf[qs][kk], o[dt][qs], 0, 0, 0);
                }
        }
        __syncthreads();   // readers done with buf[cur] AND buf[nxt] staged
    }
    // epilogue: reduce l across quads, O^T -> LDS with 1/l, coalesced out
#pragma unroll
    for (int qs = 0; qs < 2; ++qs) {
        float l = l_s[qs];
        l += __shfl_xor(l, 16);
        l += __shfl_xor(l, 32);
        float inv = 1.f / l;
#pragma unroll
        for (int dt = 0; dt < 4; ++dt) {
            bf16x4 pk;
#pragma unroll
            for (int r = 0; r < 4; ++r) pk[r] = (short)f2bf(o[dt][qs][r] * inv);
            *(bf16x4*)&myPT[(qs * 16 + ln15) * 72 + dt * 16 + quad * 4] = pk;
        }
    }
    const int bi = bh >> 4, h = bh & 15;
#pragma unroll
    for (int p = 0; p < 4; ++p) {
        int row = p * 8 + (lane >> 3);
        int cc = (lane & 7) * 8;
        short8 vv = *(const short8*)&myPT[row * 72 + cc];
        int qg = qw + row;
        *(short8*)&Aout[((size_t)bi * 2048 + qg) * 1024 + h * 64 + cc] = vv;
    }
}

// ---------------------------------------------------------------------------
// Kernel 4: out(f32) = attn_bf[8192x1024] * WoB^T + bo(f32).
// 128x128 tile, single-barrier double-buffered staging (unchanged).
// ---------------------------------------------------------------------------
__global__ __launch_bounds__(256) void outproj_k(const ushort_t* A, const ushort_t* WoB,
                                                 const float* bo, float* Out) {
    __shared__ __align__(16) ushort_t As[2][128 * 64];   // 32 KB
    __shared__ __align__(16) ushort_t Bs[2][128 * 64];   // 32 KB
    const int tid = threadIdx.x, wave = tid >> 6, lane = tid & 63;
    const int ln15 = lane & 15, quad = lane >> 4;
    const int wm = wave >> 1, wn = wave & 1;
    const int lrow = lane >> 3, lcol = (lane & 7) * 8;
    const int m0 = blockIdx.x * 128, n0 = blockIdx.y * 128;

    f32x4 acc[4][4];
#pragma unroll
    for (int i = 0; i < 4; ++i)
#pragma unroll
        for (int j = 0; j < 4; ++j)
#pragma unroll
            for (int e = 0; e < 4; ++e) acc[i][j][e] = 0.f;

    // prologue: stage k0=0 into buf 0
#pragma unroll
    for (int i = 0; i < 4; ++i) {
        int br = i * 32 + wave * 8;
        gl_lds16(A   + (size_t)(m0 + br + lrow) * 1024 + lcol, &As[0][br * 64]);
        gl_lds16(WoB + (size_t)(n0 + br + lrow) * 1024 + lcol, &Bs[0][br * 64]);
    }
    __syncthreads();

    for (int it = 0; it < 16; ++it) {
        const int cur = it & 1, nxt = cur ^ 1;
        if (it < 15) {
            const int k0 = (it + 1) * 64;
#pragma unroll
            for (int i = 0; i < 4; ++i) {
                int br = i * 32 + wave * 8;
                gl_lds16(A   + (size_t)(m0 + br + lrow) * 1024 + k0 + lcol, &As[nxt][br * 64]);
                gl_lds16(WoB + (size_t)(n0 + br + lrow) * 1024 + k0 + lcol, &Bs[nxt][br * 64]);
            }
        }
#pragma unroll
        for (int kk = 0; kk < 2; ++kk) {
            short8 a[4], b[4];
#pragma unroll
            for (int f = 0; f < 4; ++f)
                a[f] = *(const short8*)&As[cur][(wm * 64 + f * 16 + ln15) * 64 + kk * 32 + quad * 8];
#pragma unroll
            for (int f = 0; f < 4; ++f)
                b[f] = *(const short8*)&Bs[cur][(wn * 64 + f * 16 + ln15) * 64 + kk * 32 + quad * 8];
#pragma unroll
            for (int fm = 0; fm < 4; ++fm)
#pragma unroll
                for (int fn = 0; fn < 4; ++fn)
                    acc[fm][fn] = __builtin_amdgcn_mfma_f32_16x16x32_bf16(a[fm], b[fn], acc[fm][fn], 0, 0, 0);
        }
        __syncthreads();
    }
#pragma unroll
    for (int fn = 0; fn < 4; ++fn) {
        int n = n0 + wn * 64 + fn * 16 + ln15;
        float bias = bo[n];
#pragma unroll
        for (int fm = 0; fm < 4; ++fm)
#pragma unroll
            for (int r = 0; r < 4; ++r) {
                int mg = m0 + wm * 64 + fm * 16 + quad * 4 + r;
                Out[(size_t)mg * 1024 + n] = acc[fm][fn][r] + bias;
            }
    }
}

// ---------------------------------------------------------------------------
extern "C" void kernel_launch(void* const* d_in, const int* in_sizes, int n_in,
                              void* d_out, int out_size, void* d_ws, size_t ws_size,
                              hipStream_t stream) {
    (void)in_sizes; (void)n_in; (void)out_size; (void)ws_size;
    const float* inp = (const float*)d_in[0];   // [4,2048,1024] f32
    const float* Wq  = (const float*)d_in[1];   // [16,1024,64]  f32
    const float* Wk  = (const float*)d_in[2];
    const float* Wv  = (const float*)d_in[3];
    const float* Wo  = (const float*)d_in[4];   // [1024,1024]   f32
    const float* bo  = (const float*)d_in[5];   // [1024]        f32
    float* out = (float*)d_out;                  // [4,2048,1024] f32

    ushort_t* ws = (ushort_t*)d_ws;
    ushort_t* R0  = ws;                       // 8,388,608 el (inp_bf, then At)
    ushort_t* WT  = R0  + 8388608;            // [3][16][64][1024]
    ushort_t* WoB = WT  + 3145728;            // [1024][1024]
    ushort_t* Qb  = WoB + 1048576;            // [4][16][2048][64]
    ushort_t* Kb  = Qb  + 8388608;            // [4][16][2048][64]
    ushort_t* Vtb = Kb  + 8388608;            // [4][16][64][2048]

    ushort_t* inp_bf = R0;
    ushort_t* At     = R0;

    prep_k<<<5376, 256, 0, stream>>>(inp, Wo, Wq, Wk, Wv, inp_bf, WoB, WT);
    qkv_k<<<dim3(32, 24), 512, 0, stream>>>(inp_bf, WT, Qb, Kb, Vtb);
    flash_k<<<dim3(1024), 256, 0, stream>>>(Qb, Kb, Vtb, At);
    outproj_k<<<dim3(64, 8), 256, 0, stream>>>(At, WoB, bo, out);
}

// Round 3
// 234.747 us; speedup vs baseline: 1.1910x; 1.1285x over previous
//
#include <hip/hip_runtime.h>
#include <stdint.h>

typedef unsigned short ushort_t;
typedef __attribute__((ext_vector_type(8))) short short8;
typedef __attribute__((ext_vector_type(4))) short bf16x4;
typedef __attribute__((ext_vector_type(4))) float f32x4;

#define AS1 __attribute__((address_space(1)))
#define AS3 __attribute__((address_space(3)))

// async global->LDS, 16B per lane; LDS dest is wave-uniform base + lane*16
__device__ __forceinline__ void gl_lds16(const void* g, void* l) {
    __builtin_amdgcn_global_load_lds((const AS1 unsigned int*)g,
                                     (AS3 unsigned int*)l, 16, 0, 0);
}

__device__ __forceinline__ ushort_t f2bf(float f) {   // RNE f32 -> bf16
    union { float f; unsigned u; } v; v.f = f;
    unsigned r = v.u + 0x7fffu + ((v.u >> 16) & 1u);
    return (ushort_t)(r >> 16);
}

// ---------------------------------------------------------------------------
// Kernel 0 (merged prep): grid-sliced
// ---------------------------------------------------------------------------
__global__ __launch_bounds__(256) void prep_k(const float* __restrict__ inp,
                                              const float* __restrict__ Wo,
                                              const float* __restrict__ Wq,
                                              const float* __restrict__ Wk,
                                              const float* __restrict__ Wv,
                                              ushort_t* __restrict__ inp_bf,
                                              ushort_t* __restrict__ WoB,
                                              ushort_t* __restrict__ WT) {
    const int bx = blockIdx.x, tid = threadIdx.x;
    if (bx < 4608) {
        const float* src = (bx < 4096) ? inp : Wo;
        ushort_t* dst    = (bx < 4096) ? inp_bf : WoB;
        int i = ((bx < 4096 ? bx : bx - 4096) * 256 + tid) * 8;
        float4 a = *(const float4*)(src + i);
        float4 b = *(const float4*)(src + i + 4);
        short8 o;
        o[0] = (short)f2bf(a.x); o[1] = (short)f2bf(a.y);
        o[2] = (short)f2bf(a.z); o[3] = (short)f2bf(a.w);
        o[4] = (short)f2bf(b.x); o[5] = (short)f2bf(b.y);
        o[6] = (short)f2bf(b.z); o[7] = (short)f2bf(b.w);
        *(short8*)(dst + i) = o;
        return;
    }
    __shared__ ushort_t t[64 * 65];
    const int wb = bx - 4608;             // 0..767 : mat(3) x h(16) x etile(16)
    const int mat = wb >> 8;
    const int h   = (wb >> 4) & 15;
    const int et  = wb & 15;
    const float* W = (mat == 0 ? Wq : (mat == 1 ? Wk : Wv)) + h * (1024 * 64);
    const float* src = W + et * 64 * 64;
#pragma unroll
    for (int i = 0; i < 16; ++i) {
        int idx = i * 256 + tid;
        int e = idx >> 6, d = idx & 63;
        t[e * 65 + d] = f2bf(src[idx]);
    }
    __syncthreads();
    ushort_t* dst = WT + (mat * 16 + h) * (64 * 1024) + et * 64;
#pragma unroll
    for (int i = 0; i < 16; ++i) {
        int idx = i * 256 + tid;
        int d = idx >> 6, e = idx & 63;
        dst[d * 1024 + e] = t[e * 65 + d];
    }
}

// ---------------------------------------------------------------------------
// Kernel 2: UNIFIED QKV GEMM — counted-vmcnt deep pipeline (T3+T4+T5).
// Round-3 changes:
//  (1) REVERTED the XCD tile swizzle: it made each XCD's resident blocks
//      span all of A (16MB >> 4MB L2) -> FETCH 49->200MB. Natural
//      round-robin gives each XCD 4 m-tiles x 8 n-tiles = 4MB. 
//  (2) T2 chunk-XOR LDS swizzle (m173 pattern: linear gl_lds dest,
//      pre-swizzled GLOBAL source chunk, XOR'd ds_read chunk).
//      4 chunks/row: store chunk c^((row>>1)&3).
// ---------------------------------------------------------------------------
__global__ __launch_bounds__(512, 2) void qkv_k(const ushort_t* __restrict__ A,
                                                const ushort_t* __restrict__ WT,
                                                ushort_t* __restrict__ Q,
                                                ushort_t* __restrict__ K,
                                                ushort_t* __restrict__ Vt) {
    __shared__ __align__(16) ushort_t ring[49152];   // 4 x (A 256x32 + B 128x32) = 96 KB
    const int tid = threadIdx.x, wave = tid >> 6, lane = tid & 63;
    const int ln15 = lane & 15, quad = lane >> 4;
    const int wm = wave >> 1, wn = wave & 1;         // 4M x 2N waves, 64x64 each
    const int m0 = blockIdx.x * 256, n0 = blockIdx.y * 128;

    // staging coords: 512 threads, 16B chunks; chunk c -> row c>>2
    const int sa_row  = wave * 16 + (lane >> 2);
    // pre-swizzled source chunk: phys chunk (lane&3) holds logical chunk
    // (lane&3) ^ swz, swz = (row>>1)&3 = (lane>>3)&3
    const int sa_colS = (((lane & 3) ^ ((lane >> 3) & 3))) * 8;
    const int woff    = wave * 512;                  // wave-uniform LDS chunk base (elems)
    // read-side chunk XOR: row = ...16*f + ln15 -> swz = (ln15>>1)&3
    const int rchunk  = (quad ^ ((ln15 >> 1) & 3)) * 8;

    f32x4 acc[4][4];
#pragma unroll
    for (int i = 0; i < 4; ++i)
#pragma unroll
        for (int j = 0; j < 4; ++j)
#pragma unroll
            for (int e = 0; e < 4; ++e) acc[i][j][e] = 0.f;

    auto stage = [&](int t) {
        const int kb = t * 32;
        ushort_t* buf = &ring[(t & 3) * 12288];
        gl_lds16(A  + (size_t)(m0 + sa_row)       * 1024 + kb + sa_colS, buf + woff);
        gl_lds16(A  + (size_t)(m0 + 128 + sa_row) * 1024 + kb + sa_colS, buf + 4096 + woff);
        gl_lds16(WT + (size_t)(n0 + sa_row)       * 1024 + kb + sa_colS, buf + 8192 + woff);
    };

    // prologue: 3 subtiles in flight, confirm t0 (leave t1,t2 = 6 loads flying)
    stage(0); stage(1); stage(2);
    asm volatile("s_waitcnt vmcnt(6)" ::: "memory");
    __builtin_amdgcn_s_barrier();
    __builtin_amdgcn_sched_barrier(0);

    for (int t = 0; t < 32; ++t) {
        const ushort_t* buf = &ring[(t & 3) * 12288];
        short8 a[4], b[4];
#pragma unroll
        for (int f = 0; f < 4; ++f)
            a[f] = *(const short8*)&buf[(wm * 64 + f * 16 + ln15) * 32 + rchunk];
#pragma unroll
        for (int f = 0; f < 4; ++f)
            b[f] = *(const short8*)&buf[8192 + (wn * 64 + f * 16 + ln15) * 32 + rchunk];
        if (t + 3 < 32) stage(t + 3);
        // confirm subtile t+1 for next phase; counted (never 0 until tail)
        if (t < 29)       asm volatile("s_waitcnt vmcnt(6)" ::: "memory");
        else if (t == 29) asm volatile("s_waitcnt vmcnt(3)" ::: "memory");
        else if (t == 30) asm volatile("s_waitcnt vmcnt(0)" ::: "memory");
        __builtin_amdgcn_s_setprio(1);
#pragma unroll
        for (int fm = 0; fm < 4; ++fm)
#pragma unroll
            for (int fn = 0; fn < 4; ++fn)
                acc[fm][fn] = __builtin_amdgcn_mfma_f32_16x16x32_bf16(a[fm], b[fn], acc[fm][fn], 0, 0, 0);
        __builtin_amdgcn_s_setprio(0);
        __builtin_amdgcn_s_barrier();
        __builtin_amdgcn_sched_barrier(0);
    }

    const int n_base = n0 + wn * 64;          // this wave's 64-col head block
    const int mat = n_base >> 10;             // 0:Q 1:K 2:V (uniform per wave)
    const int h   = (n_base >> 6) & 15;
    if (mat < 2) {
        ushort_t* dst = (mat == 0) ? Q : K;
        const float scale = (mat == 0) ? 0.125f : 1.0f;   // 1/sqrt(64) into Q
#pragma unroll
        for (int fm = 0; fm < 4; ++fm) {
#pragma unroll
            for (int r = 0; r < 4; ++r) {
                int mg = m0 + wm * 64 + fm * 16 + quad * 4 + r;
                int bi = mg >> 11, s = mg & 2047;
                size_t base = ((size_t)(bi * 16 + h) * 2048 + s) * 64;
#pragma unroll
                for (int fn = 0; fn < 4; ++fn)
                    dst[base + fn * 16 + ln15] = f2bf(acc[fm][fn][r] * scale);
            }
        }
    } else {
        // V transposed: Vt[b][h][d][s]. Transpose through this wave's private
        // LDS scratch (ring is dead after the final barrier) so the global
        // store is short8 along s (128B contiguous per d-row).
        ushort_t* tb = &ring[wave * 6144];    // 12KB/wave >= 64*72 elems
#pragma unroll
        for (int fn = 0; fn < 4; ++fn)
#pragma unroll
            for (int fm = 0; fm < 4; ++fm) {
                bf16x4 pk;
#pragma unroll
                for (int r = 0; r < 4; ++r) pk[r] = (short)f2bf(acc[fm][fn][r]);
                // row = d (fn*16+ln15), col = s_local (fm*16+quad*4..+3)
                *(bf16x4*)&tb[(fn * 16 + ln15) * 72 + fm * 16 + quad * 4] = pk;
            }
        // wave-private region: no barrier needed, compiler orders via lgkmcnt
        const int s0 = m0 + wm * 64;
        const int bi = s0 >> 11, sb = s0 & 2047;
#pragma unroll
        for (int p = 0; p < 8; ++p) {
            int d  = p * 8 + (lane >> 3);
            int sc = (lane & 7) * 8;
            short8 vv = *(const short8*)&tb[d * 72 + sc];
            *(short8*)&Vt[((size_t)(bi * 16 + h) * 64 + d) * 2048 + sb + sc] = vv;
        }
    }
}

// ---------------------------------------------------------------------------
// Kernel 3: causal flash attention, S^T form, fixed-max softmax,
// single-barrier double-buffered K/V staging.
// Round-3 change: T2 chunk-XOR swizzle on Ks/Vts. The [row][64-elem] tiles
// have 128B row stride = full bank wrap -> 16 lanes of each quad-group hit
// the SAME bank quad on ds_read_b128 (G4's worst case). Store chunk
// c ^ (row&7) via pre-swizzled global source; read with the same XOR.
// ---------------------------------------------------------------------------
__global__ __launch_bounds__(256, 3) void flash_k(const ushort_t* Q, const ushort_t* K,
                                                  const ushort_t* Vt, ushort_t* Aout) {
    __shared__ __align__(16) ushort_t Ks[2][64 * 64];   // 16 KB
    __shared__ __align__(16) ushort_t Vts[2][64 * 64];  // 16 KB
    __shared__ __align__(16) ushort_t PT[4][32 * 72];   // 18 KB per-wave P^T
    const int tid = threadIdx.x, wave = tid >> 6, lane = tid & 63;
    const int ln15 = lane & 15, quad = lane >> 4;
    const int bx = blockIdx.x;
    const int qt = 15 - (bx >> 6);             // big tiles dispatch first
    const int bh = bx & 63;
    const int qw = qt * 128 + wave * 32;       // this wave's first q row
    const ushort_t* Kb = K + (size_t)bh * 2048 * 64;
    const ushort_t* Vb = Vt + (size_t)bh * 64 * 2048;
    ushort_t* myPT = PT[wave];
    const int srow = tid >> 3, c8 = (tid & 7) * 8;   // staging coords (LDS dest: linear)
    // pre-swizzled source chunk: phys chunk (tid&7) holds logical chunk
    // (tid&7) ^ (row&7), row&7 = (tid>>3)&7
    const int c8s  = ((tid & 7) ^ ((tid >> 3) & 7)) * 8;
    const int swr  = ln15 & 7;                 // read-side row XOR key

    // Q-fragments direct from global
    short8 qf[2][2];
    {
        const ushort_t* Qb = Q + (size_t)bh * 2048 * 64;
#pragma unroll
        for (int qs = 0; qs < 2; ++qs)
#pragma unroll
            for (int kk = 0; kk < 2; ++kk)
                qf[qs][kk] = *(const short8*)&Qb[(size_t)(qw + qs * 16 + ln15) * 64 + kk * 32 + quad * 8];
    }

    f32x4 o[4][2];
#pragma unroll
    for (int dt = 0; dt < 4; ++dt)
#pragma unroll
        for (int qs = 0; qs < 2; ++qs)
#pragma unroll
            for (int e = 0; e < 4; ++e) o[dt][qs][e] = 0.f;
    float l_s[2] = {0.f, 0.f};

    const int ktEnd = 2 * qt + 2;
    // prologue: stage kt=0 into buf 0 (source chunk pre-swizzled)
    gl_lds16(Kb + (size_t)srow * 64 + c8s,        &Ks[0][srow * 64 + c8]);
    gl_lds16(Kb + (size_t)(32 + srow) * 64 + c8s, &Ks[0][(32 + srow) * 64 + c8]);
    gl_lds16(Vb + (size_t)srow * 2048 + c8s,        &Vts[0][srow * 64 + c8]);
    gl_lds16(Vb + (size_t)(32 + srow) * 2048 + c8s, &Vts[0][(32 + srow) * 64 + c8]);
    __syncthreads();   // buf0 staged (compiler drains vmcnt before barrier)

    for (int kt = 0; kt < ktEnd; ++kt) {
        const int cur = kt & 1, nxt = cur ^ 1;
        if (kt + 1 < ktEnd) {   // prefetch next tile into the other buffer
            int kn = kt + 1;
            gl_lds16(Kb + (size_t)(kn * 64 + srow) * 64 + c8s,      &Ks[nxt][srow * 64 + c8]);
            gl_lds16(Kb + (size_t)(kn * 64 + 32 + srow) * 64 + c8s, &Ks[nxt][(32 + srow) * 64 + c8]);
            gl_lds16(Vb + (size_t)srow * 2048 + kn * 64 + c8s,        &Vts[nxt][srow * 64 + c8]);
            gl_lds16(Vb + (size_t)(32 + srow) * 2048 + kn * 64 + c8s, &Vts[nxt][(32 + srow) * 64 + c8]);
        }
        if (kt * 64 <= qw + 31) {              // wave not fully masked
            // S^T = K . Q^T   (C: row=key=quad*4+r, col=q=ln15)
            f32x4 sc[4][2];
#pragma unroll
            for (int ks = 0; ks < 4; ++ks) {
#pragma unroll
                for (int qs = 0; qs < 2; ++qs)
#pragma unroll
                    for (int e = 0; e < 4; ++e) sc[ks][qs][e] = 0.f;
#pragma unroll
                for (int kk = 0; kk < 2; ++kk) {
                    short8 kf = *(const short8*)&Ks[cur][(ks * 16 + ln15) * 64 + ((kk * 4 + quad) ^ swr) * 8];
#pragma unroll
                    for (int qs = 0; qs < 2; ++qs)
                        sc[ks][qs] = __builtin_amdgcn_mfma_f32_16x16x32_bf16(kf, qf[qs][kk], sc[ks][qs], 0, 0, 0);
                }
            }
            if (kt * 64 + 63 > qw) {           // diagonal: causal mask
#pragma unroll
                for (int ks = 0; ks < 4; ++ks)
#pragma unroll
                    for (int qs = 0; qs < 2; ++qs) {
                        int qg = qw + qs * 16 + ln15;
#pragma unroll
                        for (int r = 0; r < 4; ++r) {
                            int kg = kt * 64 + ks * 16 + quad * 4 + r;
                            if (kg > qg) sc[ks][qs][r] = -1e30f;
                        }
                    }
            }
            // fixed-max softmax: p = exp(s); per-lane l; pack P^T
#pragma unroll
            for (int qs = 0; qs < 2; ++qs) {
#pragma unroll
                for (int ks = 0; ks < 4; ++ks) {
                    bf16x4 pk;
#pragma unroll
                    for (int r = 0; r < 4; ++r) {
                        float p = __expf(sc[ks][qs][r]);
                        l_s[qs] += p;
                        pk[r] = (short)f2bf(p);
                    }
                    *(bf16x4*)&myPT[(qs * 16 + ln15) * 72 + ks * 16 + quad * 4] = pk;
                }
            }
            // O^T += V^T . P^T
            short8 pf[2][2];
#pragma unroll
            for (int qs = 0; qs < 2; ++qs)
#pragma unroll
                for (int kk = 0; kk < 2; ++kk)
                    pf[qs][kk] = *(const short8*)&myPT[(qs * 16 + ln15) * 72 + kk * 32 + quad * 8];
#pragma unroll
            for (int dt = 0; dt < 4; ++dt)
#pragma unroll
                for (int kk = 0; kk < 2; ++kk) {
                    short8 vf = *(const short8*)&Vts[cur][(dt * 16 + ln15) * 64 + ((kk * 4 + quad) ^ swr) * 8];
#pragma unroll
                    for (int qs = 0; qs < 2; ++qs)
                        o[dt][qs] = __builtin_amdgcn_mfma_f32_16x16x32_bf16(vf, pf[qs][kk], o[dt][qs], 0, 0, 0);
                }
        }
        __syncthreads();   // readers done with buf[cur] AND buf[nxt] staged
    }
    // epilogue: reduce l across quads, O^T -> LDS with 1/l, coalesced out
#pragma unroll
    for (int qs = 0; qs < 2; ++qs) {
        float l = l_s[qs];
        l += __shfl_xor(l, 16);
        l += __shfl_xor(l, 32);
        float inv = 1.f / l;
#pragma unroll
        for (int dt = 0; dt < 4; ++dt) {
            bf16x4 pk;
#pragma unroll
            for (int r = 0; r < 4; ++r) pk[r] = (short)f2bf(o[dt][qs][r] * inv);
            *(bf16x4*)&myPT[(qs * 16 + ln15) * 72 + dt * 16 + quad * 4] = pk;
        }
    }
    const int bi = bh >> 4, h = bh & 15;
#pragma unroll
    for (int p = 0; p < 4; ++p) {
        int row = p * 8 + (lane >> 3);
        int cc = (lane & 7) * 8;
        short8 vv = *(const short8*)&myPT[row * 72 + cc];
        int qg = qw + row;
        *(short8*)&Aout[((size_t)bi * 2048 + qg) * 1024 + h * 64 + cc] = vv;
    }
}

// ---------------------------------------------------------------------------
// Kernel 4: out(f32) = attn_bf[8192x1024] * WoB^T + bo(f32).
// 128x128 tile, single-barrier double-buffered staging.
// Round-3 change: same T2 chunk-XOR swizzle (128B-stride rows).
// ---------------------------------------------------------------------------
__global__ __launch_bounds__(256) void outproj_k(const ushort_t* A, const ushort_t* WoB,
                                                 const float* bo, float* Out) {
    __shared__ __align__(16) ushort_t As[2][128 * 64];   // 32 KB
    __shared__ __align__(16) ushort_t Bs[2][128 * 64];   // 32 KB
    const int tid = threadIdx.x, wave = tid >> 6, lane = tid & 63;
    const int ln15 = lane & 15, quad = lane >> 4;
    const int wm = wave >> 1, wn = wave & 1;
    const int lrow = lane >> 3, lcol = (lane & 7) * 8;
    const int lcolS = ((lane & 7) ^ (lane >> 3)) * 8;    // pre-swizzled source chunk
    const int swr   = ln15 & 7;                          // read-side row XOR key
    const int m0 = blockIdx.x * 128, n0 = blockIdx.y * 128;

    f32x4 acc[4][4];
#pragma unroll
    for (int i = 0; i < 4; ++i)
#pragma unroll
        for (int j = 0; j < 4; ++j)
#pragma unroll
            for (int e = 0; e < 4; ++e) acc[i][j][e] = 0.f;

    // prologue: stage k0=0 into buf 0
#pragma unroll
    for (int i = 0; i < 4; ++i) {
        int br = i * 32 + wave * 8;
        gl_lds16(A   + (size_t)(m0 + br + lrow) * 1024 + lcolS, &As[0][br * 64]);
        gl_lds16(WoB + (size_t)(n0 + br + lrow) * 1024 + lcolS, &Bs[0][br * 64]);
    }
    __syncthreads();

    for (int it = 0; it < 16; ++it) {
        const int cur = it & 1, nxt = cur ^ 1;
        if (it < 15) {
            const int k0 = (it + 1) * 64;
#pragma unroll
            for (int i = 0; i < 4; ++i) {
                int br = i * 32 + wave * 8;
                gl_lds16(A   + (size_t)(m0 + br + lrow) * 1024 + k0 + lcolS, &As[nxt][br * 64]);
                gl_lds16(WoB + (size_t)(n0 + br + lrow) * 1024 + k0 + lcolS, &Bs[nxt][br * 64]);
            }
        }
#pragma unroll
        for (int kk = 0; kk < 2; ++kk) {
            short8 a[4], b[4];
#pragma unroll
            for (int f = 0; f < 4; ++f)
                a[f] = *(const short8*)&As[cur][(wm * 64 + f * 16 + ln15) * 64 + ((kk * 4 + quad) ^ swr) * 8];
#pragma unroll
            for (int f = 0; f < 4; ++f)
                b[f] = *(const short8*)&Bs[cur][(wn * 64 + f * 16 + ln15) * 64 + ((kk * 4 + quad) ^ swr) * 8];
#pragma unroll
            for (int fm = 0; fm < 4; ++fm)
#pragma unroll
                for (int fn = 0; fn < 4; ++fn)
                    acc[fm][fn] = __builtin_amdgcn_mfma_f32_16x16x32_bf16(a[fm], b[fn], acc[fm][fn], 0, 0, 0);
        }
        __syncthreads();
    }
#pragma unroll
    for (int fn = 0; fn < 4; ++fn) {
        int n = n0 + wn * 64 + fn * 16 + ln15;
        float bias = bo[n];
#pragma unroll
        for (int fm = 0; fm < 4; ++fm)
#pragma unroll
            for (int r = 0; r < 4; ++r) {
                int mg = m0 + wm * 64 + fm * 16 + quad * 4 + r;
                Out[(size_t)mg * 1024 + n] = acc[fm][fn][r] + bias;
            }
    }
}

// ---------------------------------------------------------------------------
extern "C" void kernel_launch(void* const* d_in, const int* in_sizes, int n_in,
                              void* d_out, int out_size, void* d_ws, size_t ws_size,
                              hipStream_t stream) {
    (void)in_sizes; (void)n_in; (void)out_size; (void)ws_size;
    const float* inp = (const float*)d_in[0];   // [4,2048,1024] f32
    const float* Wq  = (const float*)d_in[1];   // [16,1024,64]  f32
    const float* Wk  = (const float*)d_in[2];
    const float* Wv  = (const float*)d_in[3];
    const float* Wo  = (const float*)d_in[4];   // [1024,1024]   f32
    const float* bo  = (const float*)d_in[5];   // [1024]        f32
    float* out = (float*)d_out;                  // [4,2048,1024] f32

    ushort_t* ws = (ushort_t*)d_ws;
    ushort_t* R0  = ws;                       // 8,388,608 el (inp_bf, then At)
    ushort_t* WT  = R0  + 8388608;            // [3][16][64][1024]
    ushort_t* WoB = WT  + 3145728;            // [1024][1024]
    ushort_t* Qb  = WoB + 1048576;            // [4][16][2048][64]
    ushort_t* Kb  = Qb  + 8388608;            // [4][16][2048][64]
    ushort_t* Vtb = Kb  + 8388608;            // [4][16][64][2048]

    ushort_t* inp_bf = R0;
    ushort_t* At     = R0;

    prep_k<<<5376, 256, 0, stream>>>(inp, Wo, Wq, Wk, Wv, inp_bf, WoB, WT);
    qkv_k<<<dim3(32, 24), 512, 0, stream>>>(inp_bf, WT, Qb, Kb, Vtb);
    flash_k<<<dim3(1024), 256, 0, stream>>>(Qb, Kb, Vtb, At);
    outproj_k<<<dim3(64, 8), 256, 0, stream>>>(At, WoB, bo, out);
}

// Round 4
// 231.746 us; speedup vs baseline: 1.2064x; 1.0129x over previous
//
#include <hip/hip_runtime.h>
#include <stdint.h>

typedef unsigned short ushort_t;
typedef __attribute__((ext_vector_type(8))) short short8;
typedef __attribute__((ext_vector_type(4))) short bf16x4;
typedef __attribute__((ext_vector_type(4))) float f32x4;

#define AS1 __attribute__((address_space(1)))
#define AS3 __attribute__((address_space(3)))

// async global->LDS, 16B per lane; LDS dest is wave-uniform base + lane*16
__device__ __forceinline__ void gl_lds16(const void* g, void* l) {
    __builtin_amdgcn_global_load_lds((const AS1 unsigned int*)g,
                                     (AS3 unsigned int*)l, 16, 0, 0);
}

__device__ __forceinline__ ushort_t f2bf(float f) {   // RNE f32 -> bf16
    union { float f; unsigned u; } v; v.f = f;
    unsigned r = v.u + 0x7fffu + ((v.u >> 16) & 1u);
    return (ushort_t)(r >> 16);
}

// ---------------------------------------------------------------------------
// Kernel 0 (merged prep): grid-sliced
// ---------------------------------------------------------------------------
__global__ __launch_bounds__(256) void prep_k(const float* __restrict__ inp,
                                              const float* __restrict__ Wo,
                                              const float* __restrict__ Wq,
                                              const float* __restrict__ Wk,
                                              const float* __restrict__ Wv,
                                              ushort_t* __restrict__ inp_bf,
                                              ushort_t* __restrict__ WoB,
                                              ushort_t* __restrict__ WT) {
    const int bx = blockIdx.x, tid = threadIdx.x;
    if (bx < 4608) {
        const float* src = (bx < 4096) ? inp : Wo;
        ushort_t* dst    = (bx < 4096) ? inp_bf : WoB;
        int i = ((bx < 4096 ? bx : bx - 4096) * 256 + tid) * 8;
        float4 a = *(const float4*)(src + i);
        float4 b = *(const float4*)(src + i + 4);
        short8 o;
        o[0] = (short)f2bf(a.x); o[1] = (short)f2bf(a.y);
        o[2] = (short)f2bf(a.z); o[3] = (short)f2bf(a.w);
        o[4] = (short)f2bf(b.x); o[5] = (short)f2bf(b.y);
        o[6] = (short)f2bf(b.z); o[7] = (short)f2bf(b.w);
        *(short8*)(dst + i) = o;
        return;
    }
    __shared__ ushort_t t[64 * 65];
    const int wb = bx - 4608;             // 0..767 : mat(3) x h(16) x etile(16)
    const int mat = wb >> 8;
    const int h   = (wb >> 4) & 15;
    const int et  = wb & 15;
    const float* W = (mat == 0 ? Wq : (mat == 1 ? Wk : Wv)) + h * (1024 * 64);
    const float* src = W + et * 64 * 64;
#pragma unroll
    for (int i = 0; i < 16; ++i) {
        int idx = i * 256 + tid;
        int e = idx >> 6, d = idx & 63;
        t[e * 65 + d] = f2bf(src[idx]);
    }
    __syncthreads();
    ushort_t* dst = WT + (mat * 16 + h) * (64 * 1024) + et * 64;
#pragma unroll
    for (int i = 0; i < 16; ++i) {
        int idx = i * 256 + tid;
        int d = idx >> 6, e = idx & 63;
        dst[d * 1024 + e] = t[e * 65 + d];
    }
}

// ---------------------------------------------------------------------------
// Kernel 2: UNIFIED QKV GEMM — counted-vmcnt deep pipeline (T3+T4+T5) with
// ONE-PHASE-EARLY ds_read (round-4 change): at phase t the wave ds_reads the
// fragments for phase t+1 (ping-pong reg sets), so the MFMA's lgkm wait
// lands on reads issued a full phase earlier -> LDS latency hidden.
// Invariant at top of phase t: buf[t] and buf[t+1] confirmed (vmcnt) and
// barrier-crossed; regs[t] loaded during phase t-1.
// Body: ds_read regs[t+1] <- buf[(t+1)&3]; stage(t+3); vmcnt(3)
// (confirm-ahead-2, never 0 until tail); MFMA on regs[t]; s_barrier.
// Safety: stage(t+3) overwrites slot (t-1)&3 whose last ds_reads were
// lgkm-confirmed (compiler-inserted wait before MFMA at t-1) before the
// end-of-(t-1) barrier in EVERY wave.
// ---------------------------------------------------------------------------
__global__ __launch_bounds__(512, 2) void qkv_k(const ushort_t* __restrict__ A,
                                                const ushort_t* __restrict__ WT,
                                                ushort_t* __restrict__ Q,
                                                ushort_t* __restrict__ K,
                                                ushort_t* __restrict__ Vt) {
    __shared__ __align__(16) ushort_t ring[49152];   // 4 x (A 256x32 + B 128x32) = 96 KB
    const int tid = threadIdx.x, wave = tid >> 6, lane = tid & 63;
    const int ln15 = lane & 15, quad = lane >> 4;
    const int wm = wave >> 1, wn = wave & 1;         // 4M x 2N waves, 64x64 each
    const int m0 = blockIdx.x * 256, n0 = blockIdx.y * 128;

    // staging coords: 512 threads, 16B chunks; chunk c -> row c>>2
    const int sa_row  = wave * 16 + (lane >> 2);
    // pre-swizzled source chunk: phys chunk (lane&3) holds logical chunk
    // (lane&3) ^ swz, swz = (row>>1)&3 = (lane>>3)&3
    const int sa_colS = (((lane & 3) ^ ((lane >> 3) & 3))) * 8;
    const int woff    = wave * 512;                  // wave-uniform LDS chunk base (elems)
    // read-side chunk XOR: row = ...16*f + ln15 -> swz = (ln15>>1)&3
    const int rchunk  = (quad ^ ((ln15 >> 1) & 3)) * 8;

    f32x4 acc[4][4];
#pragma unroll
    for (int i = 0; i < 4; ++i)
#pragma unroll
        for (int j = 0; j < 4; ++j)
#pragma unroll
            for (int e = 0; e < 4; ++e) acc[i][j][e] = 0.f;

    auto stage = [&](int t) {
        const int kb = t * 32;
        ushort_t* buf = &ring[(t & 3) * 12288];
        gl_lds16(A  + (size_t)(m0 + sa_row)       * 1024 + kb + sa_colS, buf + woff);
        gl_lds16(A  + (size_t)(m0 + 128 + sa_row) * 1024 + kb + sa_colS, buf + 4096 + woff);
        gl_lds16(WT + (size_t)(n0 + sa_row)       * 1024 + kb + sa_colS, buf + 8192 + woff);
    };
    auto ldfrag = [&](int t, short8 (&na)[4], short8 (&nb)[4]) {
        const ushort_t* buf = &ring[(t & 3) * 12288];
#pragma unroll
        for (int f = 0; f < 4; ++f)
            na[f] = *(const short8*)&buf[(wm * 64 + f * 16 + ln15) * 32 + rchunk];
#pragma unroll
        for (int f = 0; f < 4; ++f)
            nb[f] = *(const short8*)&buf[8192 + (wn * 64 + f * 16 + ln15) * 32 + rchunk];
    };

    // prologue: 3 subtiles in flight; confirm slots 0 AND 1 (leave slot2's 3)
    stage(0); stage(1); stage(2);
    asm volatile("s_waitcnt vmcnt(3)" ::: "memory");
    __builtin_amdgcn_s_barrier();
    __builtin_amdgcn_sched_barrier(0);

    short8 aA[4], bA[4], aB[4], bB[4];
    ldfrag(0, aA, bA);                 // regs for phase 0

    auto phase = [&](int t, short8 (&ca)[4], short8 (&cb)[4],
                     short8 (&na)[4], short8 (&nb)[4]) {
        if (t + 1 < 32) ldfrag(t + 1, na, nb);   // one-phase-early ds_read
        if (t + 3 < 32) stage(t + 3);
        // confirm slot t+2 (for next phase's ldfrag of t+2): outstanding
        // after stage(t+3) = stages t+2,t+3 = 6 loads -> wait to 3.
        if (t < 29)       asm volatile("s_waitcnt vmcnt(3)" ::: "memory");
        else if (t == 29) asm volatile("s_waitcnt vmcnt(0)" ::: "memory");
        __builtin_amdgcn_sched_barrier(0);   // pin: reads/stage/vmcnt before MFMA
        __builtin_amdgcn_s_setprio(1);
#pragma unroll
        for (int fm = 0; fm < 4; ++fm)
#pragma unroll
            for (int fn = 0; fn < 4; ++fn)
                acc[fm][fn] = __builtin_amdgcn_mfma_f32_16x16x32_bf16(ca[fm], cb[fn], acc[fm][fn], 0, 0, 0);
        __builtin_amdgcn_s_setprio(0);
        __builtin_amdgcn_s_barrier();
        __builtin_amdgcn_sched_barrier(0);
    };

    for (int t2 = 0; t2 < 32; t2 += 2) {
        phase(t2,     aA, bA, aB, bB);
        phase(t2 + 1, aB, bB, aA, bA);
    }

    const int n_base = n0 + wn * 64;          // this wave's 64-col head block
    const int mat = n_base >> 10;             // 0:Q 1:K 2:V (uniform per wave)
    const int h   = (n_base >> 6) & 15;
    if (mat < 2) {
        ushort_t* dst = (mat == 0) ? Q : K;
        const float scale = (mat == 0) ? 0.125f : 1.0f;   // 1/sqrt(64) into Q
#pragma unroll
        for (int fm = 0; fm < 4; ++fm) {
#pragma unroll
            for (int r = 0; r < 4; ++r) {
                int mg = m0 + wm * 64 + fm * 16 + quad * 4 + r;
                int bi = mg >> 11, s = mg & 2047;
                size_t base = ((size_t)(bi * 16 + h) * 2048 + s) * 64;
#pragma unroll
                for (int fn = 0; fn < 4; ++fn)
                    dst[base + fn * 16 + ln15] = f2bf(acc[fm][fn][r] * scale);
            }
        }
    } else {
        // V transposed: Vt[b][h][d][s]. Transpose through this wave's private
        // LDS scratch (ring is dead after the final barrier) so the global
        // store is short8 along s (128B contiguous per d-row).
        ushort_t* tb = &ring[wave * 6144];    // 12KB/wave >= 64*72 elems
#pragma unroll
        for (int fn = 0; fn < 4; ++fn)
#pragma unroll
            for (int fm = 0; fm < 4; ++fm) {
                bf16x4 pk;
#pragma unroll
                for (int r = 0; r < 4; ++r) pk[r] = (short)f2bf(acc[fm][fn][r]);
                // row = d (fn*16+ln15), col = s_local (fm*16+quad*4..+3)
                *(bf16x4*)&tb[(fn * 16 + ln15) * 72 + fm * 16 + quad * 4] = pk;
            }
        // wave-private region: no barrier needed, compiler orders via lgkmcnt
        const int s0 = m0 + wm * 64;
        const int bi = s0 >> 11, sb = s0 & 2047;
#pragma unroll
        for (int p = 0; p < 8; ++p) {
            int d  = p * 8 + (lane >> 3);
            int sc = (lane & 7) * 8;
            short8 vv = *(const short8*)&tb[d * 72 + sc];
            *(short8*)&Vt[((size_t)(bi * 16 + h) * 64 + d) * 2048 + sb + sc] = vv;
        }
    }
}

// ---------------------------------------------------------------------------
// Kernel 3: causal flash attention, S^T form, fixed-max softmax,
// single-barrier double-buffered K/V staging + T2 chunk-XOR swizzle on
// Ks/Vts (unchanged this round).
// ---------------------------------------------------------------------------
__global__ __launch_bounds__(256, 3) void flash_k(const ushort_t* Q, const ushort_t* K,
                                                  const ushort_t* Vt, ushort_t* Aout) {
    __shared__ __align__(16) ushort_t Ks[2][64 * 64];   // 16 KB
    __shared__ __align__(16) ushort_t Vts[2][64 * 64];  // 16 KB
    __shared__ __align__(16) ushort_t PT[4][32 * 72];   // 18 KB per-wave P^T
    const int tid = threadIdx.x, wave = tid >> 6, lane = tid & 63;
    const int ln15 = lane & 15, quad = lane >> 4;
    const int bx = blockIdx.x;
    const int qt = 15 - (bx >> 6);             // big tiles dispatch first
    const int bh = bx & 63;
    const int qw = qt * 128 + wave * 32;       // this wave's first q row
    const ushort_t* Kb = K + (size_t)bh * 2048 * 64;
    const ushort_t* Vb = Vt + (size_t)bh * 64 * 2048;
    ushort_t* myPT = PT[wave];
    const int srow = tid >> 3, c8 = (tid & 7) * 8;   // staging coords (LDS dest: linear)
    // pre-swizzled source chunk: phys chunk (tid&7) holds logical chunk
    // (tid&7) ^ (row&7), row&7 = (tid>>3)&7
    const int c8s  = ((tid & 7) ^ ((tid >> 3) & 7)) * 8;
    const int swr  = ln15 & 7;                 // read-side row XOR key

    // Q-fragments direct from global
    short8 qf[2][2];
    {
        const ushort_t* Qb = Q + (size_t)bh * 2048 * 64;
#pragma unroll
        for (int qs = 0; qs < 2; ++qs)
#pragma unroll
            for (int kk = 0; kk < 2; ++kk)
                qf[qs][kk] = *(const short8*)&Qb[(size_t)(qw + qs * 16 + ln15) * 64 + kk * 32 + quad * 8];
    }

    f32x4 o[4][2];
#pragma unroll
    for (int dt = 0; dt < 4; ++dt)
#pragma unroll
        for (int qs = 0; qs < 2; ++qs)
#pragma unroll
            for (int e = 0; e < 4; ++e) o[dt][qs][e] = 0.f;
    float l_s[2] = {0.f, 0.f};

    const int ktEnd = 2 * qt + 2;
    // prologue: stage kt=0 into buf 0 (source chunk pre-swizzled)
    gl_lds16(Kb + (size_t)srow * 64 + c8s,        &Ks[0][srow * 64 + c8]);
    gl_lds16(Kb + (size_t)(32 + srow) * 64 + c8s, &Ks[0][(32 + srow) * 64 + c8]);
    gl_lds16(Vb + (size_t)srow * 2048 + c8s,        &Vts[0][srow * 64 + c8]);
    gl_lds16(Vb + (size_t)(32 + srow) * 2048 + c8s, &Vts[0][(32 + srow) * 64 + c8]);
    __syncthreads();   // buf0 staged (compiler drains vmcnt before barrier)

    for (int kt = 0; kt < ktEnd; ++kt) {
        const int cur = kt & 1, nxt = cur ^ 1;
        if (kt + 1 < ktEnd) {   // prefetch next tile into the other buffer
            int kn = kt + 1;
            gl_lds16(Kb + (size_t)(kn * 64 + srow) * 64 + c8s,      &Ks[nxt][srow * 64 + c8]);
            gl_lds16(Kb + (size_t)(kn * 64 + 32 + srow) * 64 + c8s, &Ks[nxt][(32 + srow) * 64 + c8]);
            gl_lds16(Vb + (size_t)srow * 2048 + kn * 64 + c8s,        &Vts[nxt][srow * 64 + c8]);
            gl_lds16(Vb + (size_t)(32 + srow) * 2048 + kn * 64 + c8s, &Vts[nxt][(32 + srow) * 64 + c8]);
        }
        if (kt * 64 <= qw + 31) {              // wave not fully masked
            // S^T = K . Q^T   (C: row=key=quad*4+r, col=q=ln15)
            f32x4 sc[4][2];
#pragma unroll
            for (int ks = 0; ks < 4; ++ks) {
#pragma unroll
                for (int qs = 0; qs < 2; ++qs)
#pragma unroll
                    for (int e = 0; e < 4; ++e) sc[ks][qs][e] = 0.f;
#pragma unroll
                for (int kk = 0; kk < 2; ++kk) {
                    short8 kf = *(const short8*)&Ks[cur][(ks * 16 + ln15) * 64 + ((kk * 4 + quad) ^ swr) * 8];
#pragma unroll
                    for (int qs = 0; qs < 2; ++qs)
                        sc[ks][qs] = __builtin_amdgcn_mfma_f32_16x16x32_bf16(kf, qf[qs][kk], sc[ks][qs], 0, 0, 0);
                }
            }
            if (kt * 64 + 63 > qw) {           // diagonal: causal mask
#pragma unroll
                for (int ks = 0; ks < 4; ++ks)
#pragma unroll
                    for (int qs = 0; qs < 2; ++qs) {
                        int qg = qw + qs * 16 + ln15;
#pragma unroll
                        for (int r = 0; r < 4; ++r) {
                            int kg = kt * 64 + ks * 16 + quad * 4 + r;
                            if (kg > qg) sc[ks][qs][r] = -1e30f;
                        }
                    }
            }
            // fixed-max softmax: p = exp(s); per-lane l; pack P^T
#pragma unroll
            for (int qs = 0; qs < 2; ++qs) {
#pragma unroll
                for (int ks = 0; ks < 4; ++ks) {
                    bf16x4 pk;
#pragma unroll
                    for (int r = 0; r < 4; ++r) {
                        float p = __expf(sc[ks][qs][r]);
                        l_s[qs] += p;
                        pk[r] = (short)f2bf(p);
                    }
                    *(bf16x4*)&myPT[(qs * 16 + ln15) * 72 + ks * 16 + quad * 4] = pk;
                }
            }
            // O^T += V^T . P^T
            short8 pf[2][2];
#pragma unroll
            for (int qs = 0; qs < 2; ++qs)
#pragma unroll
                for (int kk = 0; kk < 2; ++kk)
                    pf[qs][kk] = *(const short8*)&myPT[(qs * 16 + ln15) * 72 + kk * 32 + quad * 8];
#pragma unroll
            for (int dt = 0; dt < 4; ++dt)
#pragma unroll
                for (int kk = 0; kk < 2; ++kk) {
                    short8 vf = *(const short8*)&Vts[cur][(dt * 16 + ln15) * 64 + ((kk * 4 + quad) ^ swr) * 8];
#pragma unroll
                    for (int qs = 0; qs < 2; ++qs)
                        o[dt][qs] = __builtin_amdgcn_mfma_f32_16x16x32_bf16(vf, pf[qs][kk], o[dt][qs], 0, 0, 0);
                }
        }
        __syncthreads();   // readers done with buf[cur] AND buf[nxt] staged
    }
    // epilogue: reduce l across quads, O^T -> LDS with 1/l, coalesced out
#pragma unroll
    for (int qs = 0; qs < 2; ++qs) {
        float l = l_s[qs];
        l += __shfl_xor(l, 16);
        l += __shfl_xor(l, 32);
        float inv = 1.f / l;
#pragma unroll
        for (int dt = 0; dt < 4; ++dt) {
            bf16x4 pk;
#pragma unroll
            for (int r = 0; r < 4; ++r) pk[r] = (short)f2bf(o[dt][qs][r] * inv);
            *(bf16x4*)&myPT[(qs * 16 + ln15) * 72 + dt * 16 + quad * 4] = pk;
        }
    }
    const int bi = bh >> 4, h = bh & 15;
#pragma unroll
    for (int p = 0; p < 4; ++p) {
        int row = p * 8 + (lane >> 3);
        int cc = (lane & 7) * 8;
        short8 vv = *(const short8*)&myPT[row * 72 + cc];
        int qg = qw + row;
        *(short8*)&Aout[((size_t)bi * 2048 + qg) * 1024 + h * 64 + cc] = vv;
    }
}

// ---------------------------------------------------------------------------
// Kernel 4: out(f32) = attn_bf[8192x1024] * WoB^T + bo(f32).
// 128x128 tile, single-barrier double-buffered staging + T2 chunk-XOR
// swizzle (unchanged this round).
// ---------------------------------------------------------------------------
__global__ __launch_bounds__(256) void outproj_k(const ushort_t* A, const ushort_t* WoB,
                                                 const float* bo, float* Out) {
    __shared__ __align__(16) ushort_t As[2][128 * 64];   // 32 KB
    __shared__ __align__(16) ushort_t Bs[2][128 * 64];   // 32 KB
    const int tid = threadIdx.x, wave = tid >> 6, lane = tid & 63;
    const int ln15 = lane & 15, quad = lane >> 4;
    const int wm = wave >> 1, wn = wave & 1;
    const int lrow = lane >> 3, lcol = (lane & 7) * 8;
    const int lcolS = ((lane & 7) ^ (lane >> 3)) * 8;    // pre-swizzled source chunk
    const int swr   = ln15 & 7;                          // read-side row XOR key
    const int m0 = blockIdx.x * 128, n0 = blockIdx.y * 128;

    f32x4 acc[4][4];
#pragma unroll
    for (int i = 0; i < 4; ++i)
#pragma unroll
        for (int j = 0; j < 4; ++j)
#pragma unroll
            for (int e = 0; e < 4; ++e) acc[i][j][e] = 0.f;

    // prologue: stage k0=0 into buf 0
#pragma unroll
    for (int i = 0; i < 4; ++i) {
        int br = i * 32 + wave * 8;
        gl_lds16(A   + (size_t)(m0 + br + lrow) * 1024 + lcolS, &As[0][br * 64]);
        gl_lds16(WoB + (size_t)(n0 + br + lrow) * 1024 + lcolS, &Bs[0][br * 64]);
    }
    __syncthreads();

    for (int it = 0; it < 16; ++it) {
        const int cur = it & 1, nxt = cur ^ 1;
        if (it < 15) {
            const int k0 = (it + 1) * 64;
#pragma unroll
            for (int i = 0; i < 4; ++i) {
                int br = i * 32 + wave * 8;
                gl_lds16(A   + (size_t)(m0 + br + lrow) * 1024 + k0 + lcolS, &As[nxt][br * 64]);
                gl_lds16(WoB + (size_t)(n0 + br + lrow) * 1024 + k0 + lcolS, &Bs[nxt][br * 64]);
            }
        }
#pragma unroll
        for (int kk = 0; kk < 2; ++kk) {
            short8 a[4], b[4];
#pragma unroll
            for (int f = 0; f < 4; ++f)
                a[f] = *(const short8*)&As[cur][(wm * 64 + f * 16 + ln15) * 64 + ((kk * 4 + quad) ^ swr) * 8];
#pragma unroll
            for (int f = 0; f < 4; ++f)
                b[f] = *(const short8*)&Bs[cur][(wn * 64 + f * 16 + ln15) * 64 + ((kk * 4 + quad) ^ swr) * 8];
#pragma unroll
            for (int fm = 0; fm < 4; ++fm)
#pragma unroll
                for (int fn = 0; fn < 4; ++fn)
                    acc[fm][fn] = __builtin_amdgcn_mfma_f32_16x16x32_bf16(a[fm], b[fn], acc[fm][fn], 0, 0, 0);
        }
        __syncthreads();
    }
#pragma unroll
    for (int fn = 0; fn < 4; ++fn) {
        int n = n0 + wn * 64 + fn * 16 + ln15;
        float bias = bo[n];
#pragma unroll
        for (int fm = 0; fm < 4; ++fm)
#pragma unroll
            for (int r = 0; r < 4; ++r) {
                int mg = m0 + wm * 64 + fm * 16 + quad * 4 + r;
                Out[(size_t)mg * 1024 + n] = acc[fm][fn][r] + bias;
            }
    }
}

// ---------------------------------------------------------------------------
extern "C" void kernel_launch(void* const* d_in, const int* in_sizes, int n_in,
                              void* d_out, int out_size, void* d_ws, size_t ws_size,
                              hipStream_t stream) {
    (void)in_sizes; (void)n_in; (void)out_size; (void)ws_size;
    const float* inp = (const float*)d_in[0];   // [4,2048,1024] f32
    const float* Wq  = (const float*)d_in[1];   // [16,1024,64]  f32
    const float* Wk  = (const float*)d_in[2];
    const float* Wv  = (const float*)d_in[3];
    const float* Wo  = (const float*)d_in[4];   // [1024,1024]   f32
    const float* bo  = (const float*)d_in[5];   // [1024]        f32
    float* out = (float*)d_out;                  // [4,2048,1024] f32

    ushort_t* ws = (ushort_t*)d_ws;
    ushort_t* R0  = ws;                       // 8,388,608 el (inp_bf, then At)
    ushort_t* WT  = R0  + 8388608;            // [3][16][64][1024]
    ushort_t* WoB = WT  + 3145728;            // [1024][1024]
    ushort_t* Qb  = WoB + 1048576;            // [4][16][2048][64]
    ushort_t* Kb  = Qb  + 8388608;            // [4][16][2048][64]
    ushort_t* Vtb = Kb  + 8388608;            // [4][16][64][2048]

    ushort_t* inp_bf = R0;
    ushort_t* At     = R0;

    prep_k<<<5376, 256, 0, stream>>>(inp, Wo, Wq, Wk, Wv, inp_bf, WoB, WT);
    qkv_k<<<dim3(32, 24), 512, 0, stream>>>(inp_bf, WT, Qb, Kb, Vtb);
    flash_k<<<dim3(1024), 256, 0, stream>>>(Qb, Kb, Vtb, At);
    outproj_k<<<dim3(64, 8), 256, 0, stream>>>(At, WoB, bo, out);
}

// Round 5
// 226.134 us; speedup vs baseline: 1.2363x; 1.0248x over previous
//
#include <hip/hip_runtime.h>
#include <stdint.h>

typedef unsigned short ushort_t;
typedef __attribute__((ext_vector_type(8))) short short8;
typedef __attribute__((ext_vector_type(4))) short bf16x4;
typedef __attribute__((ext_vector_type(4))) float f32x4;

#define AS1 __attribute__((address_space(1)))
#define AS3 __attribute__((address_space(3)))

// async global->LDS, 16B per lane; LDS dest is wave-uniform base + lane*16
__device__ __forceinline__ void gl_lds16(const void* g, void* l) {
    __builtin_amdgcn_global_load_lds((const AS1 unsigned int*)g,
                                     (AS3 unsigned int*)l, 16, 0, 0);
}

__device__ __forceinline__ ushort_t f2bf(float f) {   // RNE f32 -> bf16
    union { float f; unsigned u; } v; v.f = f;
    unsigned r = v.u + 0x7fffu + ((v.u >> 16) & 1u);
    return (ushort_t)(r >> 16);
}

// ---------------------------------------------------------------------------
// Kernel 0 (merged prep): grid-sliced
// ---------------------------------------------------------------------------
__global__ __launch_bounds__(256) void prep_k(const float* __restrict__ inp,
                                              const float* __restrict__ Wo,
                                              const float* __restrict__ Wq,
                                              const float* __restrict__ Wk,
                                              const float* __restrict__ Wv,
                                              ushort_t* __restrict__ inp_bf,
                                              ushort_t* __restrict__ WoB,
                                              ushort_t* __restrict__ WT) {
    const int bx = blockIdx.x, tid = threadIdx.x;
    if (bx < 4608) {
        const float* src = (bx < 4096) ? inp : Wo;
        ushort_t* dst    = (bx < 4096) ? inp_bf : WoB;
        int i = ((bx < 4096 ? bx : bx - 4096) * 256 + tid) * 8;
        float4 a = *(const float4*)(src + i);
        float4 b = *(const float4*)(src + i + 4);
        short8 o;
        o[0] = (short)f2bf(a.x); o[1] = (short)f2bf(a.y);
        o[2] = (short)f2bf(a.z); o[3] = (short)f2bf(a.w);
        o[4] = (short)f2bf(b.x); o[5] = (short)f2bf(b.y);
        o[6] = (short)f2bf(b.z); o[7] = (short)f2bf(b.w);
        *(short8*)(dst + i) = o;
        return;
    }
    __shared__ ushort_t t[64 * 65];
    const int wb = bx - 4608;             // 0..767 : mat(3) x h(16) x etile(16)
    const int mat = wb >> 8;
    const int h   = (wb >> 4) & 15;
    const int et  = wb & 15;
    const float* W = (mat == 0 ? Wq : (mat == 1 ? Wk : Wv)) + h * (1024 * 64);
    const float* src = W + et * 64 * 64;
#pragma unroll
    for (int i = 0; i < 16; ++i) {
        int idx = i * 256 + tid;
        int e = idx >> 6, d = idx & 63;
        t[e * 65 + d] = f2bf(src[idx]);
    }
    __syncthreads();
    ushort_t* dst = WT + (mat * 16 + h) * (64 * 1024) + et * 64;
#pragma unroll
    for (int i = 0; i < 16; ++i) {
        int idx = i * 256 + tid;
        int d = idx >> 6, e = idx & 63;
        dst[d * 1024 + e] = t[e * 65 + d];
    }
}

// ---------------------------------------------------------------------------
// Kernel 2: UNIFIED QKV GEMM — counted-vmcnt pipeline, RING-3 (72 KB LDS)
// so TWO blocks co-reside per CU (was 1 at 96 KB). Round-5 change: the
// cross-block implicit overlap (m114) covers in-phase LDS latency, so the
// one-phase-early ds_read (incompatible with ring-3 confirm-ahead-2 under
// counted vmcnt) is reverted.
// Schedule: phase t = { ldfrag(slot t%3); stage(t+2 -> slot (t+2)%3);
// vmcnt(3) [confirms t+1, never 0 until t=30]; MFMA; s_barrier }.
// Safety: ldfrag(t) reads data confirmed by ALL waves at phase t-1's vmcnt
// + the intervening barrier. stage(t+2) overwrites slot (t-1)%3 whose reads
// (ldfrag at t-1) were lgkm-drained before MFMA(t-1), i.e. before the
// end-of-(t-1) barrier in every wave. Loop unrolled x3 => static slots.
// ---------------------------------------------------------------------------
__global__ __launch_bounds__(512, 4) void qkv_k(const ushort_t* __restrict__ A,
                                                const ushort_t* __restrict__ WT,
                                                ushort_t* __restrict__ Q,
                                                ushort_t* __restrict__ K,
                                                ushort_t* __restrict__ Vt) {
    __shared__ __align__(16) ushort_t ring[36864];   // 3 x (A 256x32 + B 128x32) = 72 KB
    const int tid = threadIdx.x, wave = tid >> 6, lane = tid & 63;
    const int ln15 = lane & 15, quad = lane >> 4;
    const int wm = wave >> 1, wn = wave & 1;         // 4M x 2N waves, 64x64 each
    const int m0 = blockIdx.x * 256, n0 = blockIdx.y * 128;

    // staging coords: 512 threads, 16B chunks; chunk c -> row c>>2
    const int sa_row  = wave * 16 + (lane >> 2);
    // pre-swizzled source chunk: phys chunk (lane&3) holds logical chunk
    // (lane&3) ^ swz, swz = (row>>1)&3 = (lane>>3)&3
    const int sa_colS = (((lane & 3) ^ ((lane >> 3) & 3))) * 8;
    const int woff    = wave * 512;                  // wave-uniform LDS chunk base (elems)
    // read-side chunk XOR: row = ...16*f + ln15 -> swz = (ln15>>1)&3
    const int rchunk  = (quad ^ ((ln15 >> 1) & 3)) * 8;

    f32x4 acc[4][4];
#pragma unroll
    for (int i = 0; i < 4; ++i)
#pragma unroll
        for (int j = 0; j < 4; ++j)
#pragma unroll
            for (int e = 0; e < 4; ++e) acc[i][j][e] = 0.f;

    auto stage = [&](int t, ushort_t* buf) {
        const int kb = t * 32;
        gl_lds16(A  + (size_t)(m0 + sa_row)       * 1024 + kb + sa_colS, buf + woff);
        gl_lds16(A  + (size_t)(m0 + 128 + sa_row) * 1024 + kb + sa_colS, buf + 4096 + woff);
        gl_lds16(WT + (size_t)(n0 + sa_row)       * 1024 + kb + sa_colS, buf + 8192 + woff);
    };

    // prologue: 2 subtiles in flight; confirm slot 0 (leave slot 1's 3 flying)
    stage(0, &ring[0]); stage(1, &ring[12288]);
    asm volatile("s_waitcnt vmcnt(3)" ::: "memory");
    __builtin_amdgcn_s_barrier();
    __builtin_amdgcn_sched_barrier(0);

    auto phase = [&](int t, const ushort_t* bufC, ushort_t* bufS) {
        short8 a[4], b[4];
#pragma unroll
        for (int f = 0; f < 4; ++f)
            a[f] = *(const short8*)&bufC[(wm * 64 + f * 16 + ln15) * 32 + rchunk];
#pragma unroll
        for (int f = 0; f < 4; ++f)
            b[f] = *(const short8*)&bufC[8192 + (wn * 64 + f * 16 + ln15) * 32 + rchunk];
        if (t + 2 < 32) stage(t + 2, bufS);
        // confirm slot t+1 for next phase; counted (never 0 until tail)
        if (t < 30)       asm volatile("s_waitcnt vmcnt(3)" ::: "memory");
        else if (t == 30) asm volatile("s_waitcnt vmcnt(0)" ::: "memory");
        __builtin_amdgcn_sched_barrier(0);
        __builtin_amdgcn_s_setprio(1);
#pragma unroll
        for (int fm = 0; fm < 4; ++fm)
#pragma unroll
            for (int fn = 0; fn < 4; ++fn)
                acc[fm][fn] = __builtin_amdgcn_mfma_f32_16x16x32_bf16(a[fm], b[fn], acc[fm][fn], 0, 0, 0);
        __builtin_amdgcn_s_setprio(0);
        __builtin_amdgcn_s_barrier();
        __builtin_amdgcn_sched_barrier(0);
    };

    for (int t3 = 0; t3 < 30; t3 += 3) {   // static ring slots, period 3
        phase(t3,     &ring[0],     &ring[24576]);
        phase(t3 + 1, &ring[12288], &ring[0]);
        phase(t3 + 2, &ring[24576], &ring[12288]);
    }
    phase(30, &ring[0],     &ring[24576]);   // stage skipped (t+2 >= 32)
    phase(31, &ring[12288], &ring[0]);       // stage skipped

    const int n_base = n0 + wn * 64;          // this wave's 64-col head block
    const int mat = n_base >> 10;             // 0:Q 1:K 2:V (uniform per wave)
    const int h   = (n_base >> 6) & 15;
    if (mat < 2) {
        ushort_t* dst = (mat == 0) ? Q : K;
        const float scale = (mat == 0) ? 0.125f : 1.0f;   // 1/sqrt(64) into Q
#pragma unroll
        for (int fm = 0; fm < 4; ++fm) {
#pragma unroll
            for (int r = 0; r < 4; ++r) {
                int mg = m0 + wm * 64 + fm * 16 + quad * 4 + r;
                int bi = mg >> 11, s = mg & 2047;
                size_t base = ((size_t)(bi * 16 + h) * 2048 + s) * 64;
#pragma unroll
                for (int fn = 0; fn < 4; ++fn)
                    dst[base + fn * 16 + ln15] = f2bf(acc[fm][fn][r] * scale);
            }
        }
    } else {
        // V transposed: Vt[b][h][d][s]. Transpose through this wave's private
        // LDS scratch (ring is dead after the final barrier) so the global
        // store is short8 along s (128B contiguous per d-row).
        ushort_t* tb = &ring[wave * 4608];    // 4608 el/wave = 64*72 exactly
#pragma unroll
        for (int fn = 0; fn < 4; ++fn)
#pragma unroll
            for (int fm = 0; fm < 4; ++fm) {
                bf16x4 pk;
#pragma unroll
                for (int r = 0; r < 4; ++r) pk[r] = (short)f2bf(acc[fm][fn][r]);
                // row = d (fn*16+ln15), col = s_local (fm*16+quad*4..+3)
                *(bf16x4*)&tb[(fn * 16 + ln15) * 72 + fm * 16 + quad * 4] = pk;
            }
        // wave-private region: no barrier needed, compiler orders via lgkmcnt
        const int s0 = m0 + wm * 64;
        const int bi = s0 >> 11, sb = s0 & 2047;
#pragma unroll
        for (int p = 0; p < 8; ++p) {
            int d  = p * 8 + (lane >> 3);
            int sc = (lane & 7) * 8;
            short8 vv = *(const short8*)&tb[d * 72 + sc];
            *(short8*)&Vt[((size_t)(bi * 16 + h) * 64 + d) * 2048 + sb + sc] = vv;
        }
    }
}

// ---------------------------------------------------------------------------
// Kernel 3: causal flash attention, S^T form, fixed-max softmax,
// single-barrier double-buffered K/V staging + T2 chunk-XOR swizzle.
// Round-5 change: T5 setprio(1) around the QK and PV MFMA clusters —
// flash's 4 waves run at independent loop phases (the m191 regime where
// setprio measured +4-7%, vs null on lockstep GEMM).
// ---------------------------------------------------------------------------
__global__ __launch_bounds__(256, 3) void flash_k(const ushort_t* Q, const ushort_t* K,
                                                  const ushort_t* Vt, ushort_t* Aout) {
    __shared__ __align__(16) ushort_t Ks[2][64 * 64];   // 16 KB
    __shared__ __align__(16) ushort_t Vts[2][64 * 64];  // 16 KB
    __shared__ __align__(16) ushort_t PT[4][32 * 72];   // 18 KB per-wave P^T
    const int tid = threadIdx.x, wave = tid >> 6, lane = tid & 63;
    const int ln15 = lane & 15, quad = lane >> 4;
    const int bx = blockIdx.x;
    const int qt = 15 - (bx >> 6);             // big tiles dispatch first
    const int bh = bx & 63;
    const int qw = qt * 128 + wave * 32;       // this wave's first q row
    const ushort_t* Kb = K + (size_t)bh * 2048 * 64;
    const ushort_t* Vb = Vt + (size_t)bh * 64 * 2048;
    ushort_t* myPT = PT[wave];
    const int srow = tid >> 3, c8 = (tid & 7) * 8;   // staging coords (LDS dest: linear)
    // pre-swizzled source chunk: phys chunk (tid&7) holds logical chunk
    // (tid&7) ^ (row&7), row&7 = (tid>>3)&7
    const int c8s  = ((tid & 7) ^ ((tid >> 3) & 7)) * 8;
    const int swr  = ln15 & 7;                 // read-side row XOR key

    // Q-fragments direct from global
    short8 qf[2][2];
    {
        const ushort_t* Qb = Q + (size_t)bh * 2048 * 64;
#pragma unroll
        for (int qs = 0; qs < 2; ++qs)
#pragma unroll
            for (int kk = 0; kk < 2; ++kk)
                qf[qs][kk] = *(const short8*)&Qb[(size_t)(qw + qs * 16 + ln15) * 64 + kk * 32 + quad * 8];
    }

    f32x4 o[4][2];
#pragma unroll
    for (int dt = 0; dt < 4; ++dt)
#pragma unroll
        for (int qs = 0; qs < 2; ++qs)
#pragma unroll
            for (int e = 0; e < 4; ++e) o[dt][qs][e] = 0.f;
    float l_s[2] = {0.f, 0.f};

    const int ktEnd = 2 * qt + 2;
    // prologue: stage kt=0 into buf 0 (source chunk pre-swizzled)
    gl_lds16(Kb + (size_t)srow * 64 + c8s,        &Ks[0][srow * 64 + c8]);
    gl_lds16(Kb + (size_t)(32 + srow) * 64 + c8s, &Ks[0][(32 + srow) * 64 + c8]);
    gl_lds16(Vb + (size_t)srow * 2048 + c8s,        &Vts[0][srow * 64 + c8]);
    gl_lds16(Vb + (size_t)(32 + srow) * 2048 + c8s, &Vts[0][(32 + srow) * 64 + c8]);
    __syncthreads();   // buf0 staged (compiler drains vmcnt before barrier)

    for (int kt = 0; kt < ktEnd; ++kt) {
        const int cur = kt & 1, nxt = cur ^ 1;
        if (kt + 1 < ktEnd) {   // prefetch next tile into the other buffer
            int kn = kt + 1;
            gl_lds16(Kb + (size_t)(kn * 64 + srow) * 64 + c8s,      &Ks[nxt][srow * 64 + c8]);
            gl_lds16(Kb + (size_t)(kn * 64 + 32 + srow) * 64 + c8s, &Ks[nxt][(32 + srow) * 64 + c8]);
            gl_lds16(Vb + (size_t)srow * 2048 + kn * 64 + c8s,        &Vts[nxt][srow * 64 + c8]);
            gl_lds16(Vb + (size_t)(32 + srow) * 2048 + kn * 64 + c8s, &Vts[nxt][(32 + srow) * 64 + c8]);
        }
        if (kt * 64 <= qw + 31) {              // wave not fully masked
            // S^T = K . Q^T   (C: row=key=quad*4+r, col=q=ln15)
            f32x4 sc[4][2];
#pragma unroll
            for (int ks = 0; ks < 4; ++ks) {
#pragma unroll
                for (int qs = 0; qs < 2; ++qs)
#pragma unroll
                    for (int e = 0; e < 4; ++e) sc[ks][qs][e] = 0.f;
            }
            __builtin_amdgcn_s_setprio(1);
#pragma unroll
            for (int ks = 0; ks < 4; ++ks) {
#pragma unroll
                for (int kk = 0; kk < 2; ++kk) {
                    short8 kf = *(const short8*)&Ks[cur][(ks * 16 + ln15) * 64 + ((kk * 4 + quad) ^ swr) * 8];
#pragma unroll
                    for (int qs = 0; qs < 2; ++qs)
                        sc[ks][qs] = __builtin_amdgcn_mfma_f32_16x16x32_bf16(kf, qf[qs][kk], sc[ks][qs], 0, 0, 0);
                }
            }
            __builtin_amdgcn_s_setprio(0);
            if (kt * 64 + 63 > qw) {           // diagonal: causal mask
#pragma unroll
                for (int ks = 0; ks < 4; ++ks)
#pragma unroll
                    for (int qs = 0; qs < 2; ++qs) {
                        int qg = qw + qs * 16 + ln15;
#pragma unroll
                        for (int r = 0; r < 4; ++r) {
                            int kg = kt * 64 + ks * 16 + quad * 4 + r;
                            if (kg > qg) sc[ks][qs][r] = -1e30f;
                        }
                    }
            }
            // fixed-max softmax: p = exp(s); per-lane l; pack P^T
#pragma unroll
            for (int qs = 0; qs < 2; ++qs) {
#pragma unroll
                for (int ks = 0; ks < 4; ++ks) {
                    bf16x4 pk;
#pragma unroll
                    for (int r = 0; r < 4; ++r) {
                        float p = __expf(sc[ks][qs][r]);
                        l_s[qs] += p;
                        pk[r] = (short)f2bf(p);
                    }
                    *(bf16x4*)&myPT[(qs * 16 + ln15) * 72 + ks * 16 + quad * 4] = pk;
                }
            }
            // O^T += V^T . P^T
            short8 pf[2][2];
#pragma unroll
            for (int qs = 0; qs < 2; ++qs)
#pragma unroll
                for (int kk = 0; kk < 2; ++kk)
                    pf[qs][kk] = *(const short8*)&myPT[(qs * 16 + ln15) * 72 + kk * 32 + quad * 8];
            __builtin_amdgcn_s_setprio(1);
#pragma unroll
            for (int dt = 0; dt < 4; ++dt)
#pragma unroll
                for (int kk = 0; kk < 2; ++kk) {
                    short8 vf = *(const short8*)&Vts[cur][(dt * 16 + ln15) * 64 + ((kk * 4 + quad) ^ swr) * 8];
#pragma unroll
                    for (int qs = 0; qs < 2; ++qs)
                        o[dt][qs] = __builtin_amdgcn_mfma_f32_16x16x32_bf16(vf, pf[qs][kk], o[dt][qs], 0, 0, 0);
                }
            __builtin_amdgcn_s_setprio(0);
        }
        __syncthreads();   // readers done with buf[cur] AND buf[nxt] staged
    }
    // epilogue: reduce l across quads, O^T -> LDS with 1/l, coalesced out
#pragma unroll
    for (int qs = 0; qs < 2; ++qs) {
        float l = l_s[qs];
        l += __shfl_xor(l, 16);
        l += __shfl_xor(l, 32);
        float inv = 1.f / l;
#pragma unroll
        for (int dt = 0; dt < 4; ++dt) {
            bf16x4 pk;
#pragma unroll
            for (int r = 0; r < 4; ++r) pk[r] = (short)f2bf(o[dt][qs][r] * inv);
            *(bf16x4*)&myPT[(qs * 16 + ln15) * 72 + dt * 16 + quad * 4] = pk;
        }
    }
    const int bi = bh >> 4, h = bh & 15;
#pragma unroll
    for (int p = 0; p < 4; ++p) {
        int row = p * 8 + (lane >> 3);
        int cc = (lane & 7) * 8;
        short8 vv = *(const short8*)&myPT[row * 72 + cc];
        int qg = qw + row;
        *(short8*)&Aout[((size_t)bi * 2048 + qg) * 1024 + h * 64 + cc] = vv;
    }
}

// ---------------------------------------------------------------------------
// Kernel 4: out(f32) = attn_bf[8192x1024] * WoB^T + bo(f32).
// 128x128 tile, single-barrier double-buffered staging + T2 chunk-XOR
// swizzle (unchanged this round).
// ---------------------------------------------------------------------------
__global__ __launch_bounds__(256) void outproj_k(const ushort_t* A, const ushort_t* WoB,
                                                 const float* bo, float* Out) {
    __shared__ __align__(16) ushort_t As[2][128 * 64];   // 32 KB
    __shared__ __align__(16) ushort_t Bs[2][128 * 64];   // 32 KB
    const int tid = threadIdx.x, wave = tid >> 6, lane = tid & 63;
    const int ln15 = lane & 15, quad = lane >> 4;
    const int wm = wave >> 1, wn = wave & 1;
    const int lrow = lane >> 3, lcol = (lane & 7) * 8;
    const int lcolS = ((lane & 7) ^ (lane >> 3)) * 8;    // pre-swizzled source chunk
    const int swr   = ln15 & 7;                          // read-side row XOR key
    const int m0 = blockIdx.x * 128, n0 = blockIdx.y * 128;

    f32x4 acc[4][4];
#pragma unroll
    for (int i = 0; i < 4; ++i)
#pragma unroll
        for (int j = 0; j < 4; ++j)
#pragma unroll
            for (int e = 0; e < 4; ++e) acc[i][j][e] = 0.f;

    // prologue: stage k0=0 into buf 0
#pragma unroll
    for (int i = 0; i < 4; ++i) {
        int br = i * 32 + wave * 8;
        gl_lds16(A   + (size_t)(m0 + br + lrow) * 1024 + lcolS, &As[0][br * 64]);
        gl_lds16(WoB + (size_t)(n0 + br + lrow) * 1024 + lcolS, &Bs[0][br * 64]);
    }
    __syncthreads();

    for (int it = 0; it < 16; ++it) {
        const int cur = it & 1, nxt = cur ^ 1;
        if (it < 15) {
            const int k0 = (it + 1) * 64;
#pragma unroll
            for (int i = 0; i < 4; ++i) {
                int br = i * 32 + wave * 8;
                gl_lds16(A   + (size_t)(m0 + br + lrow) * 1024 + k0 + lcolS, &As[nxt][br * 64]);
                gl_lds16(WoB + (size_t)(n0 + br + lrow) * 1024 + k0 + lcolS, &Bs[nxt][br * 64]);
            }
        }
#pragma unroll
        for (int kk = 0; kk < 2; ++kk) {
            short8 a[4], b[4];
#pragma unroll
            for (int f = 0; f < 4; ++f)
                a[f] = *(const short8*)&As[cur][(wm * 64 + f * 16 + ln15) * 64 + ((kk * 4 + quad) ^ swr) * 8];
#pragma unroll
            for (int f = 0; f < 4; ++f)
                b[f] = *(const short8*)&Bs[cur][(wn * 64 + f * 16 + ln15) * 64 + ((kk * 4 + quad) ^ swr) * 8];
#pragma unroll
            for (int fm = 0; fm < 4; ++fm)
#pragma unroll
                for (int fn = 0; fn < 4; ++fn)
                    acc[fm][fn] = __builtin_amdgcn_mfma_f32_16x16x32_bf16(a[fm], b[fn], acc[fm][fn], 0, 0, 0);
        }
        __syncthreads();
    }
#pragma unroll
    for (int fn = 0; fn < 4; ++fn) {
        int n = n0 + wn * 64 + fn * 16 + ln15;
        float bias = bo[n];
#pragma unroll
        for (int fm = 0; fm < 4; ++fm)
#pragma unroll
            for (int r = 0; r < 4; ++r) {
                int mg = m0 + wm * 64 + fm * 16 + quad * 4 + r;
                Out[(size_t)mg * 1024 + n] = acc[fm][fn][r] + bias;
            }
    }
}

// ---------------------------------------------------------------------------
extern "C" void kernel_launch(void* const* d_in, const int* in_sizes, int n_in,
                              void* d_out, int out_size, void* d_ws, size_t ws_size,
                              hipStream_t stream) {
    (void)in_sizes; (void)n_in; (void)out_size; (void)ws_size;
    const float* inp = (const float*)d_in[0];   // [4,2048,1024] f32
    const float* Wq  = (const float*)d_in[1];   // [16,1024,64]  f32
    const float* Wk  = (const float*)d_in[2];
    const float* Wv  = (const float*)d_in[3];
    const float* Wo  = (const float*)d_in[4];   // [1024,1024]   f32
    const float* bo  = (const float*)d_in[5];   // [1024]        f32
    float* out = (float*)d_out;                  // [4,2048,1024] f32

    ushort_t* ws = (ushort_t*)d_ws;
    ushort_t* R0  = ws;                       // 8,388,608 el (inp_bf, then At)
    ushort_t* WT  = R0  + 8388608;            // [3][16][64][1024]
    ushort_t* WoB = WT  + 3145728;            // [1024][1024]
    ushort_t* Qb  = WoB + 1048576;            // [4][16][2048][64]
    ushort_t* Kb  = Qb  + 8388608;            // [4][16][2048][64]
    ushort_t* Vtb = Kb  + 8388608;            // [4][16][64][2048]

    ushort_t* inp_bf = R0;
    ushort_t* At     = R0;

    prep_k<<<5376, 256, 0, stream>>>(inp, Wo, Wq, Wk, Wv, inp_bf, WoB, WT);
    qkv_k<<<dim3(32, 24), 512, 0, stream>>>(inp_bf, WT, Qb, Kb, Vtb);
    flash_k<<<dim3(1024), 256, 0, stream>>>(Qb, Kb, Vtb, At);
    outproj_k<<<dim3(64, 8), 256, 0, stream>>>(At, WoB, bo, out);
}

// Round 7
// 216.522 us; speedup vs baseline: 1.2912x; 1.0444x over previous
//
#include <hip/hip_runtime.h>
#include <stdint.h>

typedef unsigned short ushort_t;
typedef __attribute__((ext_vector_type(8))) short short8;
typedef __attribute__((ext_vector_type(4))) short bf16x4;
typedef __attribute__((ext_vector_type(4))) float f32x4;

#define AS1 __attribute__((address_space(1)))
#define AS3 __attribute__((address_space(3)))

// async global->LDS, 16B per lane; LDS dest is wave-uniform base + lane*16
__device__ __forceinline__ void gl_lds16(const void* g, void* l) {
    __builtin_amdgcn_global_load_lds((const AS1 unsigned int*)g,
                                     (AS3 unsigned int*)l, 16, 0, 0);
}

__device__ __forceinline__ ushort_t f2bf(float f) {   // RNE f32 -> bf16
    union { float f; unsigned u; } v; v.f = f;
    unsigned r = v.u + 0x7fffu + ((v.u >> 16) & 1u);
    return (ushort_t)(r >> 16);
}

// packed RNE f32x2 -> bf16x2 (1 instr replaces ~8 VALU ops of manual f2bf x2)
__device__ __forceinline__ unsigned cvt_pk_bf16(float lo, float hi) {
    unsigned r;
    asm("v_cvt_pk_bf16_f32 %0, %1, %2" : "=v"(r) : "v"(lo), "v"(hi));
    return r;
}

// ---------------------------------------------------------------------------
// Kernel 0 (merged prep): grid-sliced
// ---------------------------------------------------------------------------
__global__ __launch_bounds__(256) void prep_k(const float* __restrict__ inp,
                                              const float* __restrict__ Wo,
                                              const float* __restrict__ Wq,
                                              const float* __restrict__ Wk,
                                              const float* __restrict__ Wv,
                                              ushort_t* __restrict__ inp_bf,
                                              ushort_t* __restrict__ WoB,
                                              ushort_t* __restrict__ WT) {
    const int bx = blockIdx.x, tid = threadIdx.x;
    if (bx < 4608) {
        const float* src = (bx < 4096) ? inp : Wo;
        ushort_t* dst    = (bx < 4096) ? inp_bf : WoB;
        int i = ((bx < 4096 ? bx : bx - 4096) * 256 + tid) * 8;
        float4 a = *(const float4*)(src + i);
        float4 b = *(const float4*)(src + i + 4);
        short8 o;
        o[0] = (short)f2bf(a.x); o[1] = (short)f2bf(a.y);
        o[2] = (short)f2bf(a.z); o[3] = (short)f2bf(a.w);
        o[4] = (short)f2bf(b.x); o[5] = (short)f2bf(b.y);
        o[6] = (short)f2bf(b.z); o[7] = (short)f2bf(b.w);
        *(short8*)(dst + i) = o;
        return;
    }
    __shared__ ushort_t t[64 * 65];
    const int wb = bx - 4608;             // 0..767 : mat(3) x h(16) x etile(16)
    const int mat = wb >> 8;
    const int h   = (wb >> 4) & 15;
    const int et  = wb & 15;
    const float* W = (mat == 0 ? Wq : (mat == 1 ? Wk : Wv)) + h * (1024 * 64);
    const float* src = W + et * 64 * 64;
#pragma unroll
    for (int i = 0; i < 16; ++i) {
        int idx = i * 256 + tid;
        int e = idx >> 6, d = idx & 63;
        t[e * 65 + d] = f2bf(src[idx]);
    }
    __syncthreads();
    ushort_t* dst = WT + (mat * 16 + h) * (64 * 1024) + et * 64;
#pragma unroll
    for (int i = 0; i < 16; ++i) {
        int idx = i * 256 + tid;
        int d = idx >> 6, e = idx & 63;
        dst[d * 1024 + e] = t[e * 65 + d];
    }
}

// ---------------------------------------------------------------------------
// Kernel 2: UNIFIED QKV GEMM — counted-vmcnt pipeline, RING-3 (72 KB LDS),
// 2 blocks/CU (unchanged this round).
// ---------------------------------------------------------------------------
__global__ __launch_bounds__(512, 4) void qkv_k(const ushort_t* __restrict__ A,
                                                const ushort_t* __restrict__ WT,
                                                ushort_t* __restrict__ Q,
                                                ushort_t* __restrict__ K,
                                                ushort_t* __restrict__ Vt) {
    __shared__ __align__(16) ushort_t ring[36864];   // 3 x (A 256x32 + B 128x32) = 72 KB
    const int tid = threadIdx.x, wave = tid >> 6, lane = tid & 63;
    const int ln15 = lane & 15, quad = lane >> 4;
    const int wm = wave >> 1, wn = wave & 1;         // 4M x 2N waves, 64x64 each
    const int m0 = blockIdx.x * 256, n0 = blockIdx.y * 128;

    const int sa_row  = wave * 16 + (lane >> 2);
    const int sa_colS = (((lane & 3) ^ ((lane >> 3) & 3))) * 8;
    const int woff    = wave * 512;
    const int rchunk  = (quad ^ ((ln15 >> 1) & 3)) * 8;

    f32x4 acc[4][4];
#pragma unroll
    for (int i = 0; i < 4; ++i)
#pragma unroll
        for (int j = 0; j < 4; ++j)
#pragma unroll
            for (int e = 0; e < 4; ++e) acc[i][j][e] = 0.f;

    auto stage = [&](int t, ushort_t* buf) {
        const int kb = t * 32;
        gl_lds16(A  + (size_t)(m0 + sa_row)       * 1024 + kb + sa_colS, buf + woff);
        gl_lds16(A  + (size_t)(m0 + 128 + sa_row) * 1024 + kb + sa_colS, buf + 4096 + woff);
        gl_lds16(WT + (size_t)(n0 + sa_row)       * 1024 + kb + sa_colS, buf + 8192 + woff);
    };

    stage(0, &ring[0]); stage(1, &ring[12288]);
    asm volatile("s_waitcnt vmcnt(3)" ::: "memory");
    __builtin_amdgcn_s_barrier();
    __builtin_amdgcn_sched_barrier(0);

    auto phase = [&](int t, const ushort_t* bufC, ushort_t* bufS) {
        short8 a[4], b[4];
#pragma unroll
        for (int f = 0; f < 4; ++f)
            a[f] = *(const short8*)&bufC[(wm * 64 + f * 16 + ln15) * 32 + rchunk];
#pragma unroll
        for (int f = 0; f < 4; ++f)
            b[f] = *(const short8*)&bufC[8192 + (wn * 64 + f * 16 + ln15) * 32 + rchunk];
        if (t + 2 < 32) stage(t + 2, bufS);
        if (t < 30)       asm volatile("s_waitcnt vmcnt(3)" ::: "memory");
        else if (t == 30) asm volatile("s_waitcnt vmcnt(0)" ::: "memory");
        __builtin_amdgcn_sched_barrier(0);
        __builtin_amdgcn_s_setprio(1);
#pragma unroll
        for (int fm = 0; fm < 4; ++fm)
#pragma unroll
            for (int fn = 0; fn < 4; ++fn)
                acc[fm][fn] = __builtin_amdgcn_mfma_f32_16x16x32_bf16(a[fm], b[fn], acc[fm][fn], 0, 0, 0);
        __builtin_amdgcn_s_setprio(0);
        __builtin_amdgcn_s_barrier();
        __builtin_amdgcn_sched_barrier(0);
    };

    for (int t3 = 0; t3 < 30; t3 += 3) {   // static ring slots, period 3
        phase(t3,     &ring[0],     &ring[24576]);
        phase(t3 + 1, &ring[12288], &ring[0]);
        phase(t3 + 2, &ring[24576], &ring[12288]);
    }
    phase(30, &ring[0],     &ring[24576]);
    phase(31, &ring[12288], &ring[0]);

    const int n_base = n0 + wn * 64;
    const int mat = n_base >> 10;             // 0:Q 1:K 2:V (uniform per wave)
    const int h   = (n_base >> 6) & 15;
    if (mat < 2) {
        ushort_t* dst = (mat == 0) ? Q : K;
        const float scale = (mat == 0) ? 0.125f : 1.0f;   // 1/sqrt(64) into Q
#pragma unroll
        for (int fm = 0; fm < 4; ++fm) {
#pragma unroll
            for (int r = 0; r < 4; ++r) {
                int mg = m0 + wm * 64 + fm * 16 + quad * 4 + r;
                int bi = mg >> 11, s = mg & 2047;
                size_t base = ((size_t)(bi * 16 + h) * 2048 + s) * 64;
#pragma unroll
                for (int fn = 0; fn < 4; ++fn)
                    dst[base + fn * 16 + ln15] = f2bf(acc[fm][fn][r] * scale);
            }
        }
    } else {
        ushort_t* tb = &ring[wave * 4608];    // 4608 el/wave = 64*72 exactly
#pragma unroll
        for (int fn = 0; fn < 4; ++fn)
#pragma unroll
            for (int fm = 0; fm < 4; ++fm) {
                uint2 w;
                w.x = cvt_pk_bf16(acc[fm][fn][0], acc[fm][fn][1]);
                w.y = cvt_pk_bf16(acc[fm][fn][2], acc[fm][fn][3]);
                *(uint2*)&tb[(fn * 16 + ln15) * 72 + fm * 16 + quad * 4] = w;
            }
        const int s0 = m0 + wm * 64;
        const int bi = s0 >> 11, sb = s0 & 2047;
#pragma unroll
        for (int p = 0; p < 8; ++p) {
            int d  = p * 8 + (lane >> 3);
            int sc = (lane & 7) * 8;
            short8 vv = *(const short8*)&tb[d * 72 + sc];
            *(short8*)&Vt[((size_t)(bi * 16 + h) * 64 + d) * 2048 + sb + sc] = vv;
        }
    }
}

// ---------------------------------------------------------------------------
// Kernel 3: causal flash attention, S^T form, fixed-max softmax,
// single-barrier double-buffered K/V staging + T2 chunk-XOR swizzle + T5.
// P-pack and O-pack via v_cvt_pk_bf16_f32 (2 f32 -> 1 u32, RNE,
// bit-identical to manual f2bf) — cuts the dominant VALU term.
// ---------------------------------------------------------------------------
__global__ __launch_bounds__(256, 3) void flash_k(const ushort_t* Q, const ushort_t* K,
                                                  const ushort_t* Vt, ushort_t* Aout) {
    __shared__ __align__(16) ushort_t Ks[2][64 * 64];   // 16 KB
    __shared__ __align__(16) ushort_t Vts[2][64 * 64];  // 16 KB
    __shared__ __align__(16) ushort_t PT[4][32 * 72];   // 18 KB per-wave P^T
    const int tid = threadIdx.x, wave = tid >> 6, lane = tid & 63;
    const int ln15 = lane & 15, quad = lane >> 4;
    const int bx = blockIdx.x;
    const int qt = 15 - (bx >> 6);             // big tiles dispatch first
    const int bh = bx & 63;
    const int qw = qt * 128 + wave * 32;       // this wave's first q row
    const ushort_t* Kb = K + (size_t)bh * 2048 * 64;
    const ushort_t* Vb = Vt + (size_t)bh * 64 * 2048;
    ushort_t* myPT = PT[wave];
    const int srow = tid >> 3, c8 = (tid & 7) * 8;   // staging coords (LDS dest: linear)
    const int c8s  = ((tid & 7) ^ ((tid >> 3) & 7)) * 8;
    const int swr  = ln15 & 7;                 // read-side row XOR key

    // Q-fragments direct from global
    short8 qf[2][2];
    {
        const ushort_t* Qb = Q + (size_t)bh * 2048 * 64;
#pragma unroll
        for (int qs = 0; qs < 2; ++qs)
#pragma unroll
            for (int kk = 0; kk < 2; ++kk)
                qf[qs][kk] = *(const short8*)&Qb[(size_t)(qw + qs * 16 + ln15) * 64 + kk * 32 + quad * 8];
    }

    f32x4 o[4][2];
#pragma unroll
    for (int dt = 0; dt < 4; ++dt)
#pragma unroll
        for (int qs = 0; qs < 2; ++qs)
#pragma unroll
            for (int e = 0; e < 4; ++e) o[dt][qs][e] = 0.f;
    float l_s[2] = {0.f, 0.f};

    const int ktEnd = 2 * qt + 2;
    // prologue: stage kt=0 into buf 0 (source chunk pre-swizzled)
    gl_lds16(Kb + (size_t)srow * 64 + c8s,        &Ks[0][srow * 64 + c8]);
    gl_lds16(Kb + (size_t)(32 + srow) * 64 + c8s, &Ks[0][(32 + srow) * 64 + c8]);
    gl_lds16(Vb + (size_t)srow * 2048 + c8s,        &Vts[0][srow * 64 + c8]);
    gl_lds16(Vb + (size_t)(32 + srow) * 2048 + c8s, &Vts[0][(32 + srow) * 64 + c8]);
    __syncthreads();   // buf0 staged (compiler drains vmcnt before barrier)

    for (int kt = 0; kt < ktEnd; ++kt) {
        const int cur = kt & 1, nxt = cur ^ 1;
        if (kt + 1 < ktEnd) {   // prefetch next tile into the other buffer
            int kn = kt + 1;
            gl_lds16(Kb + (size_t)(kn * 64 + srow) * 64 + c8s,      &Ks[nxt][srow * 64 + c8]);
            gl_lds16(Kb + (size_t)(kn * 64 + 32 + srow) * 64 + c8s, &Ks[nxt][(32 + srow) * 64 + c8]);
            gl_lds16(Vb + (size_t)srow * 2048 + kn * 64 + c8s,        &Vts[nxt][srow * 64 + c8]);
            gl_lds16(Vb + (size_t)(32 + srow) * 2048 + kn * 64 + c8s, &Vts[nxt][(32 + srow) * 64 + c8]);
        }
        if (kt * 64 <= qw + 31) {              // wave not fully masked
            // S^T = K . Q^T   (C: row=key=quad*4+r, col=q=ln15)
            f32x4 sc[4][2];
#pragma unroll
            for (int ks = 0; ks < 4; ++ks) {
#pragma unroll
                for (int qs = 0; qs < 2; ++qs)
#pragma unroll
                    for (int e = 0; e < 4; ++e) sc[ks][qs][e] = 0.f;
            }
            __builtin_amdgcn_s_setprio(1);
#pragma unroll
            for (int ks = 0; ks < 4; ++ks) {
#pragma unroll
                for (int kk = 0; kk < 2; ++kk) {
                    short8 kf = *(const short8*)&Ks[cur][(ks * 16 + ln15) * 64 + ((kk * 4 + quad) ^ swr) * 8];
#pragma unroll
                    for (int qs = 0; qs < 2; ++qs)
                        sc[ks][qs] = __builtin_amdgcn_mfma_f32_16x16x32_bf16(kf, qf[qs][kk], sc[ks][qs], 0, 0, 0);
                }
            }
            __builtin_amdgcn_s_setprio(0);
            if (kt * 64 + 63 > qw) {           // diagonal: causal mask
#pragma unroll
                for (int ks = 0; ks < 4; ++ks)
#pragma unroll
                    for (int qs = 0; qs < 2; ++qs) {
                        int qg = qw + qs * 16 + ln15;
#pragma unroll
                        for (int r = 0; r < 4; ++r) {
                            int kg = kt * 64 + ks * 16 + quad * 4 + r;
                            if (kg > qg) sc[ks][qs][r] = -1e30f;
                        }
                    }
            }
            // fixed-max softmax: p = exp(s); per-lane l; pack P^T via cvt_pk
#pragma unroll
            for (int qs = 0; qs < 2; ++qs) {
#pragma unroll
                for (int ks = 0; ks < 4; ++ks) {
                    float p0 = __expf(sc[ks][qs][0]);
                    float p1 = __expf(sc[ks][qs][1]);
                    float p2 = __expf(sc[ks][qs][2]);
                    float p3 = __expf(sc[ks][qs][3]);
                    l_s[qs] += (p0 + p1) + (p2 + p3);
                    uint2 w;
                    w.x = cvt_pk_bf16(p0, p1);
                    w.y = cvt_pk_bf16(p2, p3);
                    *(uint2*)&myPT[(qs * 16 + ln15) * 72 + ks * 16 + quad * 4] = w;
                }
            }
            // O^T += V^T . P^T
            short8 pf[2][2];
#pragma unroll
            for (int qs = 0; qs < 2; ++qs)
#pragma unroll
                for (int kk = 0; kk < 2; ++kk)
                    pf[qs][kk] = *(const short8*)&myPT[(qs * 16 + ln15) * 72 + kk * 32 + quad * 8];
            __builtin_amdgcn_s_setprio(1);
#pragma unroll
            for (int dt = 0; dt < 4; ++dt)
#pragma unroll
                for (int kk = 0; kk < 2; ++kk) {
                    short8 vf = *(const short8*)&Vts[cur][(dt * 16 + ln15) * 64 + ((kk * 4 + quad) ^ swr) * 8];
#pragma unroll
                    for (int qs = 0; qs < 2; ++qs)
                        o[dt][qs] = __builtin_amdgcn_mfma_f32_16x16x32_bf16(vf, pf[qs][kk], o[dt][qs], 0, 0, 0);
                }
            __builtin_amdgcn_s_setprio(0);
        }
        __syncthreads();   // readers done with buf[cur] AND buf[nxt] staged
    }
    // epilogue: reduce l across quads, O^T -> LDS with 1/l, coalesced out
#pragma unroll
    for (int qs = 0; qs < 2; ++qs) {
        float l = l_s[qs];
        l += __shfl_xor(l, 16);
        l += __shfl_xor(l, 32);
        float inv = 1.f / l;
#pragma unroll
        for (int dt = 0; dt < 4; ++dt) {
            uint2 w;
            w.x = cvt_pk_bf16(o[dt][qs][0] * inv, o[dt][qs][1] * inv);
            w.y = cvt_pk_bf16(o[dt][qs][2] * inv, o[dt][qs][3] * inv);
            *(uint2*)&myPT[(qs * 16 + ln15) * 72 + dt * 16 + quad * 4] = w;
        }
    }
    const int bi = bh >> 4, h = bh & 15;
#pragma unroll
    for (int p = 0; p < 4; ++p) {
        int row = p * 8 + (lane >> 3);
        int cc = (lane & 7) * 8;
        short8 vv = *(const short8*)&myPT[row * 72 + cc];
        int qg = qw + row;
        *(short8*)&Aout[((size_t)bi * 2048 + qg) * 1024 + h * 64 + cc] = vv;
    }
}

// ---------------------------------------------------------------------------
// Kernel 4: out(f32) = attn_bf[8192x1024] * WoB^T + bo(f32).
// Ported to the verified qkv ring-3 counted-vmcnt pipeline (identical
// K=1024/BK=32 loop; only the epilogue and grid differ).
// 256x128 tile, 512 threads, 72 KB LDS -> 2 blocks/CU capacity.
// ---------------------------------------------------------------------------
__global__ __launch_bounds__(512, 4) void outproj_k(const ushort_t* __restrict__ A,
                                                    const ushort_t* __restrict__ WoB,
                                                    const float* __restrict__ bo,
                                                    float* __restrict__ Out) {
    __shared__ __align__(16) ushort_t ring[36864];   // 3 x (A 256x32 + B 128x32) = 72 KB
    const int tid = threadIdx.x, wave = tid >> 6, lane = tid & 63;
    const int ln15 = lane & 15, quad = lane >> 4;
    const int wm = wave >> 1, wn = wave & 1;         // 4M x 2N waves, 64x64 each
    const int m0 = blockIdx.x * 256, n0 = blockIdx.y * 128;

    const int sa_row  = wave * 16 + (lane >> 2);
    const int sa_colS = (((lane & 3) ^ ((lane >> 3) & 3))) * 8;
    const int woff    = wave * 512;
    const int rchunk  = (quad ^ ((ln15 >> 1) & 3)) * 8;

    f32x4 acc[4][4];
#pragma unroll
    for (int i = 0; i < 4; ++i)
#pragma unroll
        for (int j = 0; j < 4; ++j)
#pragma unroll
            for (int e = 0; e < 4; ++e) acc[i][j][e] = 0.f;

    auto stage = [&](int t, ushort_t* buf) {
        const int kb = t * 32;
        gl_lds16(A   + (size_t)(m0 + sa_row)       * 1024 + kb + sa_colS, buf + woff);
        gl_lds16(A   + (size_t)(m0 + 128 + sa_row) * 1024 + kb + sa_colS, buf + 4096 + woff);
        gl_lds16(WoB + (size_t)(n0 + sa_row)       * 1024 + kb + sa_colS, buf + 8192 + woff);
    };

    stage(0, &ring[0]); stage(1, &ring[12288]);
    asm volatile("s_waitcnt vmcnt(3)" ::: "memory");
    __builtin_amdgcn_s_barrier();
    __builtin_amdgcn_sched_barrier(0);

    auto phase = [&](int t, const ushort_t* bufC, ushort_t* bufS) {
        short8 a[4], b[4];
#pragma unroll
        for (int f = 0; f < 4; ++f)
            a[f] = *(const short8*)&bufC[(wm * 64 + f * 16 + ln15) * 32 + rchunk];
#pragma unroll
        for (int f = 0; f < 4; ++f)
            b[f] = *(const short8*)&bufC[8192 + (wn * 64 + f * 16 + ln15) * 32 + rchunk];
        if (t + 2 < 32) stage(t + 2, bufS);
        if (t < 30)       asm volatile("s_waitcnt vmcnt(3)" ::: "memory");
        else if (t == 30) asm volatile("s_waitcnt vmcnt(0)" ::: "memory");
        __builtin_amdgcn_sched_barrier(0);
        __builtin_amdgcn_s_setprio(1);
#pragma unroll
        for (int fm = 0; fm < 4; ++fm)
#pragma unroll
            for (int fn = 0; fn < 4; ++fn)
                acc[fm][fn] = __builtin_amdgcn_mfma_f32_16x16x32_bf16(a[fm], b[fn], acc[fm][fn], 0, 0, 0);
        __builtin_amdgcn_s_setprio(0);
        __builtin_amdgcn_s_barrier();
        __builtin_amdgcn_sched_barrier(0);
    };

    for (int t3 = 0; t3 < 30; t3 += 3) {   // static ring slots, period 3
        phase(t3,     &ring[0],     &ring[24576]);
        phase(t3 + 1, &ring[12288], &ring[0]);
        phase(t3 + 2, &ring[24576], &ring[12288]);
    }
    phase(30, &ring[0],     &ring[24576]);
    phase(31, &ring[12288], &ring[0]);

    const int nb = n0 + wn * 64;
    float bias[4];
#pragma unroll
    for (int fn = 0; fn < 4; ++fn) bias[fn] = bo[nb + fn * 16 + ln15];
#pragma unroll
    for (int fm = 0; fm < 4; ++fm)
#pragma unroll
        for (int r = 0; r < 4; ++r) {
            int mg = m0 + wm * 64 + fm * 16 + quad * 4 + r;
#pragma unroll
            for (int fn = 0; fn < 4; ++fn)
                Out[(size_t)mg * 1024 + nb + fn * 16 + ln15] = acc[fm][fn][r] + bias[fn];
        }
}

// ---------------------------------------------------------------------------
extern "C" void kernel_launch(void* const* d_in, const int* in_sizes, int n_in,
                              void* d_out, int out_size, void* d_ws, size_t ws_size,
                              hipStream_t stream) {
    (void)in_sizes; (void)n_in; (void)out_size; (void)ws_size;
    const float* inp = (const float*)d_in[0];   // [4,2048,1024] f32
    const float* Wq  = (const float*)d_in[1];   // [16,1024,64]  f32
    const float* Wk  = (const float*)d_in[2];
    const float* Wv  = (const float*)d_in[3];
    const float* Wo  = (const float*)d_in[4];   // [1024,1024]   f32
    const float* bo  = (const float*)d_in[5];   // [1024]        f32
    float* out = (float*)d_out;                  // [4,2048,1024] f32

    ushort_t* ws = (ushort_t*)d_ws;
    ushort_t* R0  = ws;                       // 8,388,608 el (inp_bf, then At)
    ushort_t* WT  = R0  + 8388608;            // [3][16][64][1024]
    ushort_t* WoB = WT  + 3145728;            // [1024][1024]
    ushort_t* Qb  = WoB + 1048576;            // [4][16][2048][64]
    ushort_t* Kb  = Qb  + 8388608;            // [4][16][2048][64]
    ushort_t* Vtb = Kb  + 8388608;            // [4][16][64][2048]

    ushort_t* inp_bf = R0;
    ushort_t* At     = R0;

    prep_k<<<5376, 256, 0, stream>>>(inp, Wo, Wq, Wk, Wv, inp_bf, WoB, WT);
    qkv_k<<<dim3(32, 24), 512, 0, stream>>>(inp_bf, WT, Qb, Kb, Vtb);
    flash_k<<<dim3(1024), 256, 0, stream>>>(Qb, Kb, Vtb, At);
    outproj_k<<<dim3(32, 8), 512, 0, stream>>>(At, WoB, bo, out);
}

// Round 8
// 214.241 us; speedup vs baseline: 1.3050x; 1.0106x over previous
//
#include <hip/hip_runtime.h>
#include <stdint.h>

typedef unsigned short ushort_t;
typedef __attribute__((ext_vector_type(8))) short short8;
typedef __attribute__((ext_vector_type(4))) short bf16x4;
typedef __attribute__((ext_vector_type(4))) float f32x4;
typedef __attribute__((ext_vector_type(16))) float f32x16;

#define AS1 __attribute__((address_space(1)))
#define AS3 __attribute__((address_space(3)))

// async global->LDS, 16B per lane; LDS dest is wave-uniform base + lane*16
__device__ __forceinline__ void gl_lds16(const void* g, void* l) {
    __builtin_amdgcn_global_load_lds((const AS1 unsigned int*)g,
                                     (AS3 unsigned int*)l, 16, 0, 0);
}

__device__ __forceinline__ ushort_t f2bf(float f) {   // RNE f32 -> bf16
    union { float f; unsigned u; } v; v.f = f;
    unsigned r = v.u + 0x7fffu + ((v.u >> 16) & 1u);
    return (ushort_t)(r >> 16);
}

// packed RNE f32x2 -> bf16x2
__device__ __forceinline__ unsigned cvt_pk_bf16(float lo, float hi) {
    unsigned r;
    asm("v_cvt_pk_bf16_f32 %0, %1, %2" : "=v"(r) : "v"(lo), "v"(hi));
    return r;
}

// ---------------------------------------------------------------------------
// Kernel 0 (merged prep): grid-sliced
// ---------------------------------------------------------------------------
__global__ __launch_bounds__(256) void prep_k(const float* __restrict__ inp,
                                              const float* __restrict__ Wo,
                                              const float* __restrict__ Wq,
                                              const float* __restrict__ Wk,
                                              const float* __restrict__ Wv,
                                              ushort_t* __restrict__ inp_bf,
                                              ushort_t* __restrict__ WoB,
                                              ushort_t* __restrict__ WT) {
    const int bx = blockIdx.x, tid = threadIdx.x;
    if (bx < 4608) {
        const float* src = (bx < 4096) ? inp : Wo;
        ushort_t* dst    = (bx < 4096) ? inp_bf : WoB;
        int i = ((bx < 4096 ? bx : bx - 4096) * 256 + tid) * 8;
        float4 a = *(const float4*)(src + i);
        float4 b = *(const float4*)(src + i + 4);
        short8 o;
        o[0] = (short)f2bf(a.x); o[1] = (short)f2bf(a.y);
        o[2] = (short)f2bf(a.z); o[3] = (short)f2bf(a.w);
        o[4] = (short)f2bf(b.x); o[5] = (short)f2bf(b.y);
        o[6] = (short)f2bf(b.z); o[7] = (short)f2bf(b.w);
        *(short8*)(dst + i) = o;
        return;
    }
    __shared__ ushort_t t[64 * 65];
    const int wb = bx - 4608;             // 0..767 : mat(3) x h(16) x etile(16)
    const int mat = wb >> 8;
    const int h   = (wb >> 4) & 15;
    const int et  = wb & 15;
    const float* W = (mat == 0 ? Wq : (mat == 1 ? Wk : Wv)) + h * (1024 * 64);
    const float* src = W + et * 64 * 64;
#pragma unroll
    for (int i = 0; i < 16; ++i) {
        int idx = i * 256 + tid;
        int e = idx >> 6, d = idx & 63;
        t[e * 65 + d] = f2bf(src[idx]);
    }
    __syncthreads();
    ushort_t* dst = WT + (mat * 16 + h) * (64 * 1024) + et * 64;
#pragma unroll
    for (int i = 0; i < 16; ++i) {
        int idx = i * 256 + tid;
        int d = idx >> 6, e = idx & 63;
        dst[d * 1024 + e] = t[e * 65 + d];
    }
}

// ---------------------------------------------------------------------------
// Kernel 2: UNIFIED QKV GEMM — counted-vmcnt pipeline, RING-3 (72 KB LDS),
// 2 blocks/CU (unchanged this round).
// ---------------------------------------------------------------------------
__global__ __launch_bounds__(512, 4) void qkv_k(const ushort_t* __restrict__ A,
                                                const ushort_t* __restrict__ WT,
                                                ushort_t* __restrict__ Q,
                                                ushort_t* __restrict__ K,
                                                ushort_t* __restrict__ Vt) {
    __shared__ __align__(16) ushort_t ring[36864];   // 3 x (A 256x32 + B 128x32) = 72 KB
    const int tid = threadIdx.x, wave = tid >> 6, lane = tid & 63;
    const int ln15 = lane & 15, quad = lane >> 4;
    const int wm = wave >> 1, wn = wave & 1;         // 4M x 2N waves, 64x64 each
    const int m0 = blockIdx.x * 256, n0 = blockIdx.y * 128;

    const int sa_row  = wave * 16 + (lane >> 2);
    const int sa_colS = (((lane & 3) ^ ((lane >> 3) & 3))) * 8;
    const int woff    = wave * 512;
    const int rchunk  = (quad ^ ((ln15 >> 1) & 3)) * 8;

    f32x4 acc[4][4];
#pragma unroll
    for (int i = 0; i < 4; ++i)
#pragma unroll
        for (int j = 0; j < 4; ++j)
#pragma unroll
            for (int e = 0; e < 4; ++e) acc[i][j][e] = 0.f;

    auto stage = [&](int t, ushort_t* buf) {
        const int kb = t * 32;
        gl_lds16(A  + (size_t)(m0 + sa_row)       * 1024 + kb + sa_colS, buf + woff);
        gl_lds16(A  + (size_t)(m0 + 128 + sa_row) * 1024 + kb + sa_colS, buf + 4096 + woff);
        gl_lds16(WT + (size_t)(n0 + sa_row)       * 1024 + kb + sa_colS, buf + 8192 + woff);
    };

    stage(0, &ring[0]); stage(1, &ring[12288]);
    asm volatile("s_waitcnt vmcnt(3)" ::: "memory");
    __builtin_amdgcn_s_barrier();
    __builtin_amdgcn_sched_barrier(0);

    auto phase = [&](int t, const ushort_t* bufC, ushort_t* bufS) {
        short8 a[4], b[4];
#pragma unroll
        for (int f = 0; f < 4; ++f)
            a[f] = *(const short8*)&bufC[(wm * 64 + f * 16 + ln15) * 32 + rchunk];
#pragma unroll
        for (int f = 0; f < 4; ++f)
            b[f] = *(const short8*)&bufC[8192 + (wn * 64 + f * 16 + ln15) * 32 + rchunk];
        if (t + 2 < 32) stage(t + 2, bufS);
        if (t < 30)       asm volatile("s_waitcnt vmcnt(3)" ::: "memory");
        else if (t == 30) asm volatile("s_waitcnt vmcnt(0)" ::: "memory");
        __builtin_amdgcn_sched_barrier(0);
        __builtin_amdgcn_s_setprio(1);
#pragma unroll
        for (int fm = 0; fm < 4; ++fm)
#pragma unroll
            for (int fn = 0; fn < 4; ++fn)
                acc[fm][fn] = __builtin_amdgcn_mfma_f32_16x16x32_bf16(a[fm], b[fn], acc[fm][fn], 0, 0, 0);
        __builtin_amdgcn_s_setprio(0);
        __builtin_amdgcn_s_barrier();
        __builtin_amdgcn_sched_barrier(0);
    };

    for (int t3 = 0; t3 < 30; t3 += 3) {   // static ring slots, period 3
        phase(t3,     &ring[0],     &ring[24576]);
        phase(t3 + 1, &ring[12288], &ring[0]);
        phase(t3 + 2, &ring[24576], &ring[12288]);
    }
    phase(30, &ring[0],     &ring[24576]);
    phase(31, &ring[12288], &ring[0]);

    const int n_base = n0 + wn * 64;
    const int mat = n_base >> 10;             // 0:Q 1:K 2:V (uniform per wave)
    const int h   = (n_base >> 6) & 15;
    if (mat < 2) {
        ushort_t* dst = (mat == 0) ? Q : K;
        const float scale = (mat == 0) ? 0.125f : 1.0f;   // 1/sqrt(64) into Q
#pragma unroll
        for (int fm = 0; fm < 4; ++fm) {
#pragma unroll
            for (int r = 0; r < 4; ++r) {
                int mg = m0 + wm * 64 + fm * 16 + quad * 4 + r;
                int bi = mg >> 11, s = mg & 2047;
                size_t base = ((size_t)(bi * 16 + h) * 2048 + s) * 64;
#pragma unroll
                for (int fn = 0; fn < 4; ++fn)
                    dst[base + fn * 16 + ln15] = f2bf(acc[fm][fn][r] * scale);
            }
        }
    } else {
        ushort_t* tb = &ring[wave * 4608];    // 4608 el/wave = 64*72 exactly
#pragma unroll
        for (int fn = 0; fn < 4; ++fn)
#pragma unroll
            for (int fm = 0; fm < 4; ++fm) {
                uint2 w;
                w.x = cvt_pk_bf16(acc[fm][fn][0], acc[fm][fn][1]);
                w.y = cvt_pk_bf16(acc[fm][fn][2], acc[fm][fn][3]);
                *(uint2*)&tb[(fn * 16 + ln15) * 72 + fm * 16 + quad * 4] = w;
            }
        const int s0 = m0 + wm * 64;
        const int bi = s0 >> 11, sb = s0 & 2047;
#pragma unroll
        for (int p = 0; p < 8; ++p) {
            int d  = p * 8 + (lane >> 3);
            int sc = (lane & 7) * 8;
            short8 vv = *(const short8*)&tb[d * 72 + sc];
            *(short8*)&Vt[((size_t)(bi * 16 + h) * 64 + d) * 2048 + sb + sc] = vv;
        }
    }
}

// ---------------------------------------------------------------------------
// Kernel 3: causal flash attention — ROUND-8 REWRITE to 32x32x16 MFMA with
// FULLY IN-REGISTER P (no P^T LDS round-trip).
//   QK: sc32 = mfma_32x32x16(kf, qf)  -> C: col=q(lane&31), row=key=
//       (r&3)+8(r>>2)+4h  (h = lane>>5)  [m74/m101 verified layout]
//   P->PV-B redistribution: pack pairs with cvt_pk, then ONE
//   v_permlane32_swap_b32(W[4x],W[4x+2]) yields BOTH B-words w0 (dst_a) and
//   w2 (dst_b); ditto (W[4x+1],W[4x+3]) -> w1/w3. 8 swaps/kt replace
//   8 ds_write + 4 ds_read + lgkm stalls.
//   PV: o32[dt] = mfma_32x32x16(vf, pb) accumulating O^T.
// PT buffer deleted: LDS = 32 KB -> 4 blocks/CU (launch_bounds(256,4)).
// O-epilogue transposes through the dead KVs buffers.
// ---------------------------------------------------------------------------
__global__ __launch_bounds__(256, 4) void flash_k(const ushort_t* Q, const ushort_t* K,
                                                  const ushort_t* Vt, ushort_t* Aout) {
    __shared__ __align__(16) ushort_t KVs[2][2][64 * 64];  // [buf][K/V] = 32 KB
    const int tid = threadIdx.x, wave = tid >> 6, lane = tid & 63;
    const int ln31 = lane & 31, h = lane >> 5;
    const int bx = blockIdx.x;
    const int qt = 15 - (bx >> 6);             // big tiles dispatch first
    const int bh = bx & 63;
    const int qw = qt * 128 + wave * 32;       // this wave's first q row
    const ushort_t* Kb = K + (size_t)bh * 2048 * 64;
    const ushort_t* Vb = Vt + (size_t)bh * 64 * 2048;
    const int srow = tid >> 3, c8 = (tid & 7) * 8;   // staging (LDS dest: linear)
    const int c8s  = ((tid & 7) ^ ((tid >> 3) & 7)) * 8;  // pre-swizzled source
    const int swr  = ln31 & 7;                 // read-side row XOR key

    // Q fragments: B-operand of 32x32x16: lane (q=ln31,h) holds Q[qw+q][c*16+h*8+j]
    short8 qf[4];
    {
        const ushort_t* Qb = Q + (size_t)bh * 2048 * 64;
#pragma unroll
        for (int c = 0; c < 4; ++c)
            qf[c] = *(const short8*)&Qb[(size_t)(qw + ln31) * 64 + c * 16 + h * 8];
    }

    f32x16 o[2];
#pragma unroll
    for (int dt = 0; dt < 2; ++dt)
#pragma unroll
        for (int e = 0; e < 16; ++e) o[dt][e] = 0.f;
    float l_s = 0.f;

    const int ktEnd = 2 * qt + 2;
    // prologue: stage kt=0 into buf 0
    gl_lds16(Kb + (size_t)srow * 64 + c8s,          &KVs[0][0][srow * 64 + c8]);
    gl_lds16(Kb + (size_t)(32 + srow) * 64 + c8s,   &KVs[0][0][(32 + srow) * 64 + c8]);
    gl_lds16(Vb + (size_t)srow * 2048 + c8s,        &KVs[0][1][srow * 64 + c8]);
    gl_lds16(Vb + (size_t)(32 + srow) * 2048 + c8s, &KVs[0][1][(32 + srow) * 64 + c8]);
    __syncthreads();

    for (int kt = 0; kt < ktEnd; ++kt) {
        const int cur = kt & 1, nxt = cur ^ 1;
        if (kt + 1 < ktEnd) {   // prefetch next tile into the other buffer
            int kn = kt + 1;
            gl_lds16(Kb + (size_t)(kn * 64 + srow) * 64 + c8s,        &KVs[nxt][0][srow * 64 + c8]);
            gl_lds16(Kb + (size_t)(kn * 64 + 32 + srow) * 64 + c8s,   &KVs[nxt][0][(32 + srow) * 64 + c8]);
            gl_lds16(Vb + (size_t)srow * 2048 + kn * 64 + c8s,        &KVs[nxt][1][srow * 64 + c8]);
            gl_lds16(Vb + (size_t)(32 + srow) * 2048 + kn * 64 + c8s, &KVs[nxt][1][(32 + srow) * 64 + c8]);
        }
        if (kt * 64 <= qw + 31) {              // wave not fully masked (uniform)
            const ushort_t* Ksc = KVs[cur][0];
            const ushort_t* Vsc = KVs[cur][1];
            unsigned W[2][8];                  // pack words per 32-key tile
            const bool diag = (kt * 64 + 63 > qw);
            const int qg = qw + ln31;
#pragma unroll
            for (int kt2 = 0; kt2 < 2; ++kt2) {
                f32x16 sc;
#pragma unroll
                for (int e = 0; e < 16; ++e) sc[e] = 0.f;
                __builtin_amdgcn_s_setprio(1);
#pragma unroll
                for (int c = 0; c < 4; ++c) {
                    short8 kf = *(const short8*)&Ksc[(kt2 * 32 + ln31) * 64 + ((2 * c + h) ^ swr) * 8];
                    sc = __builtin_amdgcn_mfma_f32_32x32x16_bf16(kf, qf[c], sc, 0, 0, 0);
                }
                __builtin_amdgcn_s_setprio(0);
                if (diag) {                    // causal mask (diagonal tiles)
#pragma unroll
                    for (int r = 0; r < 16; ++r) {
                        int kg = kt * 64 + kt2 * 32 + (r & 3) + 8 * (r >> 2) + 4 * h;
                        if (kg > qg) sc[r] = -1e30f;
                    }
                }
                // fixed-max softmax: exp + accumulate l + pack pairs
#pragma unroll
                for (int g = 0; g < 4; ++g) {
                    float p0 = __expf(sc[4 * g + 0]);
                    float p1 = __expf(sc[4 * g + 1]);
                    float p2 = __expf(sc[4 * g + 2]);
                    float p3 = __expf(sc[4 * g + 3]);
                    l_s += (p0 + p1) + (p2 + p3);
                    W[kt2][2 * g]     = cvt_pk_bf16(p0, p1);
                    W[kt2][2 * g + 1] = cvt_pk_bf16(p2, p3);
                }
            }
            // in-register P redistribution: swap fills two B-words at once
            short8 pb[4];
#pragma unroll
            for (int t = 0; t < 2; ++t)
#pragma unroll
                for (int x = 0; x < 2; ++x) {
                    unsigned a0 = W[t][4 * x + 0], b0 = W[t][4 * x + 2];
                    unsigned a1 = W[t][4 * x + 1], b1 = W[t][4 * x + 3];
                    asm volatile("v_permlane32_swap_b32 %0, %1" : "+v"(a0), "+v"(b0));
                    asm volatile("v_permlane32_swap_b32 %0, %1" : "+v"(a1), "+v"(b1));
                    union { unsigned u[4]; short8 s; } u;
                    u.u[0] = a0; u.u[1] = a1; u.u[2] = b0; u.u[3] = b1;
                    pb[t * 2 + x] = u.s;
                }
            // O^T += V^T . P^T
            __builtin_amdgcn_s_setprio(1);
#pragma unroll
            for (int dt = 0; dt < 2; ++dt)
#pragma unroll
                for (int x = 0; x < 4; ++x) {
                    short8 vf = *(const short8*)&Vsc[(dt * 32 + ln31) * 64 + ((2 * x + h) ^ swr) * 8];
                    o[dt] = __builtin_amdgcn_mfma_f32_32x32x16_bf16(vf, pb[x], o[dt], 0, 0, 0);
                }
            __builtin_amdgcn_s_setprio(0);
        }
        __syncthreads();   // readers done with buf[cur] AND buf[nxt] staged
    }
    // epilogue: l across halves; O^T -> LDS (KVs reused) with 1/l; coalesced out
    l_s += __shfl_xor(l_s, 32);
    float inv = 1.f / l_s;
    ushort_t* myO = &KVs[0][0][0] + wave * 2304;   // 32 q x stride 72 per wave
#pragma unroll
    for (int dt = 0; dt < 2; ++dt)
#pragma unroll
        for (int g = 0; g < 4; ++g) {
            unsigned w0 = cvt_pk_bf16(o[dt][4 * g + 0] * inv, o[dt][4 * g + 1] * inv);
            unsigned w1 = cvt_pk_bf16(o[dt][4 * g + 2] * inv, o[dt][4 * g + 3] * inv);
            int d0 = 8 * g + 4 * h + 32 * dt;      // rows d0,d0+1 / d0+2,d0+3
            *(unsigned*)&myO[ln31 * 72 + d0]     = w0;
            *(unsigned*)&myO[ln31 * 72 + d0 + 2] = w1;
        }
    const int bi = bh >> 4, hh = bh & 15;
#pragma unroll
    for (int p = 0; p < 4; ++p) {
        int row = p * 8 + (lane >> 3);
        int cc = (lane & 7) * 8;
        short8 vv = *(const short8*)&myO[row * 72 + cc];
        int qg2 = qw + row;
        *(short8*)&Aout[((size_t)bi * 2048 + qg2) * 1024 + hh * 64 + cc] = vv;
    }
}

// ---------------------------------------------------------------------------
// Kernel 4: out(f32) = attn_bf[8192x1024] * WoB^T + bo(f32).
// ring-3 counted-vmcnt pipeline (unchanged this round).
// ---------------------------------------------------------------------------
__global__ __launch_bounds__(512, 4) void outproj_k(const ushort_t* __restrict__ A,
                                                    const ushort_t* __restrict__ WoB,
                                                    const float* __restrict__ bo,
                                                    float* __restrict__ Out) {
    __shared__ __align__(16) ushort_t ring[36864];   // 3 x (A 256x32 + B 128x32) = 72 KB
    const int tid = threadIdx.x, wave = tid >> 6, lane = tid & 63;
    const int ln15 = lane & 15, quad = lane >> 4;
    const int wm = wave >> 1, wn = wave & 1;         // 4M x 2N waves, 64x64 each
    const int m0 = blockIdx.x * 256, n0 = blockIdx.y * 128;

    const int sa_row  = wave * 16 + (lane >> 2);
    const int sa_colS = (((lane & 3) ^ ((lane >> 3) & 3))) * 8;
    const int woff    = wave * 512;
    const int rchunk  = (quad ^ ((ln15 >> 1) & 3)) * 8;

    f32x4 acc[4][4];
#pragma unroll
    for (int i = 0; i < 4; ++i)
#pragma unroll
        for (int j = 0; j < 4; ++j)
#pragma unroll
            for (int e = 0; e < 4; ++e) acc[i][j][e] = 0.f;

    auto stage = [&](int t, ushort_t* buf) {
        const int kb = t * 32;
        gl_lds16(A   + (size_t)(m0 + sa_row)       * 1024 + kb + sa_colS, buf + woff);
        gl_lds16(A   + (size_t)(m0 + 128 + sa_row) * 1024 + kb + sa_colS, buf + 4096 + woff);
        gl_lds16(WoB + (size_t)(n0 + sa_row)       * 1024 + kb + sa_colS, buf + 8192 + woff);
    };

    stage(0, &ring[0]); stage(1, &ring[12288]);
    asm volatile("s_waitcnt vmcnt(3)" ::: "memory");
    __builtin_amdgcn_s_barrier();
    __builtin_amdgcn_sched_barrier(0);

    auto phase = [&](int t, const ushort_t* bufC, ushort_t* bufS) {
        short8 a[4], b[4];
#pragma unroll
        for (int f = 0; f < 4; ++f)
            a[f] = *(const short8*)&bufC[(wm * 64 + f * 16 + ln15) * 32 + rchunk];
#pragma unroll
        for (int f = 0; f < 4; ++f)
            b[f] = *(const short8*)&bufC[8192 + (wn * 64 + f * 16 + ln15) * 32 + rchunk];
        if (t + 2 < 32) stage(t + 2, bufS);
        if (t < 30)       asm volatile("s_waitcnt vmcnt(3)" ::: "memory");
        else if (t == 30) asm volatile("s_waitcnt vmcnt(0)" ::: "memory");
        __builtin_amdgcn_sched_barrier(0);
        __builtin_amdgcn_s_setprio(1);
#pragma unroll
        for (int fm = 0; fm < 4; ++fm)
#pragma unroll
            for (int fn = 0; fn < 4; ++fn)
                acc[fm][fn] = __builtin_amdgcn_mfma_f32_16x16x32_bf16(a[fm], b[fn], acc[fm][fn], 0, 0, 0);
        __builtin_amdgcn_s_setprio(0);
        __builtin_amdgcn_s_barrier();
        __builtin_amdgcn_sched_barrier(0);
    };

    for (int t3 = 0; t3 < 30; t3 += 3) {   // static ring slots, period 3
        phase(t3,     &ring[0],     &ring[24576]);
        phase(t3 + 1, &ring[12288], &ring[0]);
        phase(t3 + 2, &ring[24576], &ring[12288]);
    }
    phase(30, &ring[0],     &ring[24576]);
    phase(31, &ring[12288], &ring[0]);

    const int nb = n0 + wn * 64;
    float bias[4];
#pragma unroll
    for (int fn = 0; fn < 4; ++fn) bias[fn] = bo[nb + fn * 16 + ln15];
#pragma unroll
    for (int fm = 0; fm < 4; ++fm)
#pragma unroll
        for (int r = 0; r < 4; ++r) {
            int mg = m0 + wm * 64 + fm * 16 + quad * 4 + r;
#pragma unroll
            for (int fn = 0; fn < 4; ++fn)
                Out[(size_t)mg * 1024 + nb + fn * 16 + ln15] = acc[fm][fn][r] + bias[fn];
        }
}

// ---------------------------------------------------------------------------
extern "C" void kernel_launch(void* const* d_in, const int* in_sizes, int n_in,
                              void* d_out, int out_size, void* d_ws, size_t ws_size,
                              hipStream_t stream) {
    (void)in_sizes; (void)n_in; (void)out_size; (void)ws_size;
    const float* inp = (const float*)d_in[0];   // [4,2048,1024] f32
    const float* Wq  = (const float*)d_in[1];   // [16,1024,64]  f32
    const float* Wk  = (const float*)d_in[2];
    const float* Wv  = (const float*)d_in[3];
    const float* Wo  = (const float*)d_in[4];   // [1024,1024]   f32
    const float* bo  = (const float*)d_in[5];   // [1024]        f32
    float* out = (float*)d_out;                  // [4,2048,1024] f32

    ushort_t* ws = (ushort_t*)d_ws;
    ushort_t* R0  = ws;                       // 8,388,608 el (inp_bf, then At)
    ushort_t* WT  = R0  + 8388608;            // [3][16][64][1024]
    ushort_t* WoB = WT  + 3145728;            // [1024][1024]
    ushort_t* Qb  = WoB + 1048576;            // [4][16][2048][64]
    ushort_t* Kb  = Qb  + 8388608;            // [4][16][2048][64]
    ushort_t* Vtb = Kb  + 8388608;            // [4][16][64][2048]

    ushort_t* inp_bf = R0;
    ushort_t* At     = R0;

    prep_k<<<5376, 256, 0, stream>>>(inp, Wo, Wq, Wk, Wv, inp_bf, WoB, WT);
    qkv_k<<<dim3(32, 24), 512, 0, stream>>>(inp_bf, WT, Qb, Kb, Vtb);
    flash_k<<<dim3(1024), 256, 0, stream>>>(Qb, Kb, Vtb, At);
    outproj_k<<<dim3(32, 8), 512, 0, stream>>>(At, WoB, bo, out);
}